// Round 16
// baseline (257.036 us; speedup 1.0000x reference)
//
#include <hip/hip_runtime.h>
#include <stdint.h>

#define H_ 1024
#define NH_ 16
#define HD_ 64
#define B_ 4
#define S_ 2048
#define M_ (B_*S_)

typedef unsigned short u16;
typedef __attribute__((ext_vector_type(4))) unsigned short u16x4;
typedef __attribute__((ext_vector_type(8))) short bf16x8;
typedef __attribute__((ext_vector_type(4))) float f32x4;
typedef __attribute__((ext_vector_type(16))) float f32x16;
typedef __attribute__((ext_vector_type(4))) unsigned int u32x4;
typedef __attribute__((ext_vector_type(4))) int i32x4;

#define AS1 __attribute__((address_space(1)))
#define AS3 __attribute__((address_space(3)))

__device__ __forceinline__ void gload16(const void* g, void* l) {
  __builtin_amdgcn_global_load_lds((const AS1 void*)g, (AS3 void*)l, 16, 0, 0);
}

__device__ __forceinline__ u16 f2bf(float f) {
  union { float f; uint32_t u; } v; v.f = f;
  uint32_t u = v.u + 0x7FFFu + ((v.u >> 16) & 1u);
  return (u16)(u >> 16);
}

static __device__ __forceinline__ f32x4 mfma16(bf16x8 a, bf16x8 b, f32x4 c) {
  return __builtin_amdgcn_mfma_f32_16x16x32_bf16(a, b, c, 0, 0, 0);
}
static __device__ __forceinline__ f32x16 mfma32(bf16x8 a, bf16x8 b, f32x16 c) {
  return __builtin_amdgcn_mfma_f32_32x32x16_bf16(a, b, c, 0, 0, 0);
}

__device__ __forceinline__ int cvtpk(float lo, float hi) {
  int r;
  asm("v_cvt_pk_bf16_f32 %0, %1, %2" : "=v"(r) : "v"(lo), "v"(hi));
  return r;
}
__device__ __forceinline__ void plswap(int& a, int& b) {
  asm volatile("v_permlane32_swap_b32 %0, %1" : "+v"(a), "+v"(b));
}
#if __has_builtin(__builtin_amdgcn_exp2f)
#define EXP2F __builtin_amdgcn_exp2f
#else
#define EXP2F exp2f
#endif

// hw blockIdx -> logical id, grouping logical-contiguous blocks on one XCD (nwg%8==0)
__device__ __forceinline__ int xcd_swz(int bid, int nwg) {
  return (bid & 7) * (nwg >> 3) + (bid >> 3);
}

// ---------------- merged prep: hs->bf16 | mask->madd+bitmap | W->W^T bf16 ----------------
// bid ranges: [0,4096) hs cvt; [4096,4100) mask; [4100,5124) weight transpose.

__global__ __launch_bounds__(256) void prep_kernel(const float* __restrict__ in, u16* __restrict__ out,
                                                   const float* __restrict__ mask, float* __restrict__ madd_g,
                                                   uint32_t* __restrict__ nzbits,
                                                   const float* __restrict__ Wq, const float* __restrict__ Wk,
                                                   const float* __restrict__ Wv, const float* __restrict__ Wo,
                                                   u16* __restrict__ wt) {
  __shared__ float tile[64][65];
  const int bid = blockIdx.x, t = threadIdx.x;
  if (bid < 4096) {
    int i = bid * 256 + t;   // each thread: 8 elems
    const f32x4* p = (const f32x4*)in;
    f32x4 a = p[2*i], b = p[2*i+1];
    u32x4 o;
    o.x = (uint32_t)f2bf(a.x) | ((uint32_t)f2bf(a.y) << 16);
    o.y = (uint32_t)f2bf(a.z) | ((uint32_t)f2bf(a.w) << 16);
    o.z = (uint32_t)f2bf(b.x) | ((uint32_t)f2bf(b.y) << 16);
    o.w = (uint32_t)f2bf(b.z) | ((uint32_t)f2bf(b.w) << 16);
    ((u32x4*)out)[i] = o;
  } else if (bid < 4100) {
    const int mb = bid - 4096;                // 0..3
    int i = mb * 256 + t;                     // 1024 threads x 8 = 8192 mask elems
    f32x4 a = ((const f32x4*)mask)[2*i], b4 = ((const f32x4*)mask)[2*i+1];
    f32x4 ma, mb4;
    ma.x = (1.0f - a.x) * -3.0e38f;  ma.y = (1.0f - a.y) * -3.0e38f;
    ma.z = (1.0f - a.z) * -3.0e38f;  ma.w = (1.0f - a.w) * -3.0e38f;
    mb4.x = (1.0f - b4.x) * -3.0e38f; mb4.y = (1.0f - b4.y) * -3.0e38f;
    mb4.z = (1.0f - b4.z) * -3.0e38f; mb4.w = (1.0f - b4.w) * -3.0e38f;
    ((f32x4*)madd_g)[2*i] = ma;  ((f32x4*)madd_g)[2*i+1] = mb4;
    if (mb == 0) {  // per-(b, kv-tile) nonzero flags
      if (t < B_) nzbits[t] = 0u;
      __syncthreads();
      if (t < B_*32) {
        int b = t >> 5, kt = t & 31;
        const float* mrow = mask + (size_t)b * S_ + kt*64;
        uint32_t nz = 0;
        for (int c = 0; c < 64; ++c) nz |= (mrow[c] != 1.0f) ? 1u : 0u;
        if (nz) atomicOr(&nzbits[b], 1u << kt);
      }
    }
  } else {
    const int w = bid - 4100;                 // 0..1023
    const int p = w >> 8, ti = w & 255, tr = ti >> 4, tc = ti & 15;
    const float* W = (p == 0) ? Wq : (p == 1) ? Wk : (p == 2) ? Wv : Wo;
#pragma unroll
    for (int it = 0; it < 16; ++it) {
      int idx = it * 256 + t, r = idx >> 6, c = idx & 63;
      tile[r][c] = W[(size_t)(tr*64 + r) * H_ + tc*64 + c];
    }
    __syncthreads();
    u16* outp = wt + (size_t)p * H_ * H_;
#pragma unroll
    for (int it = 0; it < 16; ++it) {
      int idx = it * 256 + t, r = idx >> 6, c = idx & 63;
      outp[(size_t)(tc*64 + r) * H_ + tr*64 + c] = f2bf(tile[c][r]);
    }
  }
}

// ---------------- GEMM v6 (B-only LDS): 128x128 block, wave tile 64x64, BK=32 --------
// A fragments load straight from L2 to registers (per-lane b128 gathers; A's per-XCD
// slice is 2MB -> L2-resident via swizzle), double-buffered: aN prefetched during
// step k, consumed at k+1. B keeps R12's DMA staging (2 gload16/thread, [2][128][32]
// linear LDS, counted vmcnt + raw barriers). LDS traffic per step halves (16KB->8KB);
// LDS block = 16KB -> occupancy (the L2-reuse knob, R14/R15 lesson) preserved.
// vmcnt(6) = 2 B-DMAs + 4 A-prefetches allowed outstanding; dummy loads at kt=31
// keep the count uniform.

__device__ __forceinline__ void gemm_tile(const u16* __restrict__ A, const u16* __restrict__ Bt,
                                          int m0, int n0, u16* Bs, f32x4 acc[4][4]) {
  const int tid = threadIdx.x;
  const int lane = tid & 63, wave = tid >> 6;
  const int wr = wave >> 1, wc = wave & 1;
  const int l15 = lane & 15, l4 = lane >> 4;
  const int r0 = tid >> 2, c0 = (tid & 3) * 8;
  const u16* Bp0 = Bt + (size_t)(n0 + r0) * H_ + c0;
  const u16* Bp1 = Bt + (size_t)(n0 + 64 + r0) * H_ + c0;
  const u16* Ap = A + (size_t)(m0 + wr*64 + l15) * H_ + l4*8;   // A frag base (per-lane)
#define GSTAGE_B(bb, k0) do { \
    gload16(Bp0 + (k0), Bs + (bb)*4096 + (size_t)tid * 8); \
    gload16(Bp1 + (k0), Bs + (bb)*4096 + 2048 + (size_t)tid * 8); \
  } while (0)
#define ALOAD(dst, k0) do { \
    _Pragma("unroll") \
    for (int m = 0; m < 4; ++m) \
      dst[m] = *(const bf16x8*)(Ap + (size_t)(m*16) * H_ + (k0)); \
  } while (0)
  bf16x8 aC[4], aN[4];
  GSTAGE_B(0, 0);
  ALOAD(aC, 0);
  for (int kt = 0; kt < 32; ++kt) {
    const int cur = kt & 1;
    const int nk = ((kt + 1) & 31) * 32;    // kt=31: dummy (k=0) keeps vmcnt uniform
    GSTAGE_B(cur ^ 1, nk);
    ALOAD(aN, nk);
    asm volatile("s_waitcnt vmcnt(6)\n\ts_barrier" ::: "memory");  // aC + B[cur] complete
    const u16* Bb = Bs + cur*4096;
    bf16x8 bfr[4];
#pragma unroll
    for (int n = 0; n < 4; ++n) bfr[n] = *(const bf16x8*)&Bb[(wc*64 + n*16 + l15) * 32 + l4*8];
#pragma unroll
    for (int m = 0; m < 4; ++m)
#pragma unroll
      for (int n = 0; n < 4; ++n)
        acc[m][n] = mfma16(aC[m], bfr[n], acc[m][n]);
    asm volatile("s_barrier" ::: "memory");  // all waves done reading B[cur]
#pragma unroll
    for (int m = 0; m < 4; ++m) aC[m] = aN[m];
  }
  asm volatile("s_waitcnt vmcnt(0)" ::: "memory");   // drain dummy stage
#undef GSTAGE_B
#undef ALOAD
}

// QKV: C (8192 x 3072). Q (prescaled by 0.125*log2e), K -> [b][h][s][d]; V -> [b][h][d][s]
// with V^T stores packed u16x4 along s (r=0..3 contiguous) to cut write amplification.
__global__ __launch_bounds__(256) void gemm_qkv_kernel(const u16* __restrict__ hs16, const u16* __restrict__ wt,
                                                       const float* __restrict__ bq, const float* __restrict__ bk,
                                                       const float* __restrict__ bv, u16* __restrict__ qkv16) {
  __shared__ __align__(16) u16 Bs[2*128*32];
  f32x4 acc[4][4] = {};
  const int lg = xcd_swz(blockIdx.x, 1536);
  const int m0 = (lg / 24) * 128, n0 = (lg % 24) * 128;
  gemm_tile(hs16, wt, m0, n0, Bs, acc);
  const int tid = threadIdx.x, lane = tid & 63, wave = tid >> 6;
  const int wr = wave >> 1, wc = wave & 1, l15 = lane & 15, l4 = lane >> 4;
  const int p = n0 >> 10;
  const float* bias = (p == 0) ? bq : (p == 1) ? bk : bv;
  const float qsc = (p == 0) ? 0.18033688f : 1.0f;   // 0.125 * log2(e)
  u16* base = qkv16 + (size_t)p * ((size_t)B_*NH_*S_*HD_);
  if (p == 2) {
    const int b = m0 >> 11;
#pragma unroll
    for (int n = 0; n < 4; ++n) {
      int ncol = (n0 & 1023) + wc*64 + n*16 + l15;
      int h = ncol >> 6, d = ncol & 63;
      float bsv = bias[ncol];
#pragma unroll
      for (int m = 0; m < 4; ++m) {
        int s0 = (m0 & 2047) + wr*64 + m*16 + l4*4;
        u16x4 pk;
#pragma unroll
        for (int r = 0; r < 4; ++r) pk[r] = f2bf(acc[m][n][r] + bsv);
        *(u16x4*)(base + (((size_t)b*NH_ + h)*HD_ + d)*S_ + s0) = pk;
      }
    }
  } else {
#pragma unroll
    for (int n = 0; n < 4; ++n) {
      int ncol = (n0 & 1023) + wc*64 + n*16 + l15;
      int h = ncol >> 6, d = ncol & 63;
      float bsv = bias[ncol];
#pragma unroll
      for (int m = 0; m < 4; ++m) {
#pragma unroll
        for (int r = 0; r < 4; ++r) {
          int row = m0 + wr*64 + m*16 + l4*4 + r;
          int b = row >> 11, s = row & 2047;
          base[(((size_t)b*NH_ + h)*S_ + s)*HD_ + d] = f2bf((acc[m][n][r] + bsv) * qsc);
        }
      }
    }
  }
}

// out-proj: C = ctx16 @ Wo + bo + residual(hs) -> fp32 xout
__global__ __launch_bounds__(256) void gemm_out_kernel(const u16* __restrict__ ctx16, const u16* __restrict__ wo,
                                                       const float* __restrict__ bo, const float* __restrict__ hs,
                                                       float* __restrict__ xout) {
  __shared__ __align__(16) u16 Bs[2*128*32];
  f32x4 acc[4][4] = {};
  const int lg = xcd_swz(blockIdx.x, 512);
  const int m0 = (lg / 8) * 128, n0 = (lg % 8) * 128;
  gemm_tile(ctx16, wo, m0, n0, Bs, acc);
  const int tid = threadIdx.x, lane = tid & 63, wave = tid >> 6;
  const int wr = wave >> 1, wc = wave & 1, l15 = lane & 15, l4 = lane >> 4;
#pragma unroll
  for (int n = 0; n < 4; ++n) {
    int col = n0 + wc*64 + n*16 + l15;
    float bsv = bo[col];
#pragma unroll
    for (int m = 0; m < 4; ++m) {
#pragma unroll
      for (int r = 0; r < 4; ++r) {
        int row = m0 + wr*64 + m*16 + l4*4 + r;
        size_t off = (size_t)row * H_ + col;
        xout[off] = acc[m][n][r] + bsv + hs[off];
      }
    }
  }
}

// ---------------- flash attention (R12 exact): 4 waves x 64 q-rows, chainless softmax --
// 2-deep staging (vmcnt(4)), raw exp2, VALU l-sum, epilogue Sc broadcast. Proven <80us.

__global__ __launch_bounds__(256, 2) void attn_kernel(const u16* __restrict__ q_, const u16* __restrict__ k_,
                                                      const u16* __restrict__ vt_, const float* __restrict__ madd_g,
                                                      const uint32_t* __restrict__ nzbits,
                                                      u16* __restrict__ ctx16) {
  __shared__ __align__(16) u16 Ks[2][64*64], Vs[2][64*64];
  __shared__ __align__(16) float Sc[4][64];
  const int lgid = xcd_swz(blockIdx.x, 512);
  const int qb = lgid & 7, bh = lgid >> 3, h = bh & 15, b = bh >> 4;
  const int tid = threadIdx.x, lane = tid & 63, wave = tid >> 6;
  const int l31 = lane & 31, hi = lane >> 5;
  const size_t headoff = ((size_t)b * NH_ + h) * ((size_t)S_ * HD_);
  const u16* Q  = q_ + headoff;
  const u16* K  = k_ + headoff;
  const u16* Vt = vt_ + headoff;     // [d][s]
  const uint32_t nzb = nzbits[b];
  const int qbase = qb*256 + wave*64;
  bf16x8 qfA[4], qfB[4];             // strip A rows qbase+l31, strip B rows qbase+32+l31
#pragma unroll
  for (int st = 0; st < 4; ++st) {
    qfA[st] = *(const bf16x8*)(Q + (size_t)(qbase + l31) * HD_ + st*16 + hi*8);
    qfB[st] = *(const bf16x8*)(Q + (size_t)(qbase + 32 + l31) * HD_ + st*16 + hi*8);
  }
  f32x16 O00 = {}, O01 = {}, O10 = {}, O11 = {};
  float lA = 0.f, lB = 0.f;
  const int srow = tid >> 3, sch = tid & 7;
  const int gch = sch ^ (srow & 7);           // inverse-XOR source chunk (involution)
  const int swzA = l31 & 7;                   // read-side row&7

#define STAGE(bb, kt) do { \
    const u16* Kt_ = K + (size_t)(kt) * 64 * HD_; \
    _Pragma("unroll") \
    for (int c = 0; c < 2; ++c) { \
      int row = c*32 + srow; \
      gload16(Kt_ + (size_t)row * HD_ + gch*8, &Ks[bb][c*2048 + (size_t)tid*8]); \
      gload16(Vt + (size_t)row * S_ + (kt)*64 + gch*8, &Vs[bb][c*2048 + (size_t)tid*8]); \
    } \
  } while (0)

  STAGE(0, 0);
  __syncthreads();   // prologue full drain: tile 0 staged

  for (int kt = 0; kt < 32; ++kt) {
    const int cur = kt & 1;
    const int nxt = (kt + 1) & 31;  // kt=31 stages a dummy (tile 0) to keep vmcnt uniform
    STAGE(cur ^ 1, nxt);
    asm volatile("s_waitcnt vmcnt(4)\n\ts_barrier" ::: "memory");
    // ---- QK^T: S^T[kv][q] for both strips; K frags shared ----
    f32x16 sA0 = {}, sA1 = {}, sB0 = {}, sB1 = {};
    __builtin_amdgcn_s_setprio(1);
#pragma unroll
    for (int st = 0; st < 4; ++st) {
      const int kch = ((2*st + hi) ^ swzA) * 8;
      bf16x8 kf0 = *(const bf16x8*)&Ks[cur][l31*64 + kch];
      bf16x8 kf1 = *(const bf16x8*)&Ks[cur][(32 + l31)*64 + kch];
      sA0 = mfma32(kf0, qfA[st], sA0);
      sA1 = mfma32(kf1, qfA[st], sA1);
      sB0 = mfma32(kf0, qfB[st], sB0);
      sB1 = mfma32(kf1, qfB[st], sB1);
    }
    __builtin_amdgcn_s_setprio(0);
    // ---- mask add (rare path), then raw exp2 (no max subtraction) ----
    if ((nzb >> kt) & 1u) {
#pragma unroll
      for (int t = 0; t < 2; ++t) {
        f32x16& sa = t ? sA1 : sA0;
        f32x16& sb2 = t ? sB1 : sB0;
#pragma unroll
        for (int bq = 0; bq < 4; ++bq) {
          f32x4 md = *(const f32x4*)(madd_g + (size_t)b * S_ + kt*64 + t*32 + bq*8 + hi*4);
#pragma unroll
          for (int a = 0; a < 4; ++a) { sa[bq*4 + a] += md[a]; sb2[bq*4 + a] += md[a]; }
        }
      }
    }
#pragma unroll
    for (int r = 0; r < 16; ++r) sA0[r] = EXP2F(sA0[r]);
#pragma unroll
    for (int r = 0; r < 16; ++r) sA1[r] = EXP2F(sA1[r]);
#pragma unroll
    for (int r = 0; r < 16; ++r) sB0[r] = EXP2F(sB0[r]);
#pragma unroll
    for (int r = 0; r < 16; ++r) sB1[r] = EXP2F(sB1[r]);
    // ---- l via in-register add tree (independent of PV; epilogue-only consumer) ----
    {
      float v[16];
#pragma unroll
      for (int r = 0; r < 16; ++r) v[r] = sA0[r] + sA1[r];
#pragma unroll
      for (int r = 0; r < 8; ++r) v[r] += v[r+8];
#pragma unroll
      for (int r = 0; r < 4; ++r) v[r] += v[r+4];
      float rs_ = (v[0] + v[1]) + (v[2] + v[3]);
      int a0 = __float_as_int(rs_), b0 = a0; plswap(a0, b0);
      lA += __int_as_float(a0) + __int_as_float(b0);
#pragma unroll
      for (int r = 0; r < 16; ++r) v[r] = sB0[r] + sB1[r];
#pragma unroll
      for (int r = 0; r < 8; ++r) v[r] += v[r+8];
#pragma unroll
      for (int r = 0; r < 4; ++r) v[r] += v[r+4];
      rs_ = (v[0] + v[1]) + (v[2] + v[3]);
      int a1 = __float_as_int(rs_), b1 = a1; plswap(a1, b1);
      lB += __int_as_float(a1) + __int_as_float(b1);
    }
    // ---- pack P -> bf16 frags (cvt_pk + permlane32_swap); PV; V frags shared ----
    __builtin_amdgcn_s_setprio(1);
#pragma unroll
    for (int ks = 0; ks < 4; ++ks) {
      const f32x16& sa = (ks < 2) ? sA0 : sA1;
      const f32x16& sb2 = (ks < 2) ? sB0 : sB1;
      const int p = ks & 1;
      int pa0 = cvtpk(sa[8*p+0], sa[8*p+1]);
      int pa1 = cvtpk(sa[8*p+2], sa[8*p+3]);
      int pa2 = cvtpk(sa[8*p+4], sa[8*p+5]);
      int pa3 = cvtpk(sa[8*p+6], sa[8*p+7]);
      plswap(pa0, pa2); plswap(pa1, pa3);
      union { i32x4 i; bf16x8 hv; } ua; ua.i = (i32x4){pa0, pa1, pa2, pa3};
      int pb0 = cvtpk(sb2[8*p+0], sb2[8*p+1]);
      int pb1 = cvtpk(sb2[8*p+2], sb2[8*p+3]);
      int pb2 = cvtpk(sb2[8*p+4], sb2[8*p+5]);
      int pb3 = cvtpk(sb2[8*p+6], sb2[8*p+7]);
      plswap(pb0, pb2); plswap(pb1, pb3);
      union { i32x4 i; bf16x8 hv; } ub; ub.i = (i32x4){pb0, pb1, pb2, pb3};
      const int vch = ((2*ks + hi) ^ swzA) * 8;
      bf16x8 vb0 = *(const bf16x8*)&Vs[cur][l31*64 + vch];
      bf16x8 vb1 = *(const bf16x8*)&Vs[cur][(32 + l31)*64 + vch];
      O00 = mfma32(ua.hv, vb0, O00);
      O01 = mfma32(ua.hv, vb1, O01);
      O10 = mfma32(ub.hv, vb0, O10);
      O11 = mfma32(ub.hv, vb1, O11);
    }
    __builtin_amdgcn_s_setprio(0);
    asm volatile("s_barrier" ::: "memory");  // all waves done reading buf[cur]
  }
  asm volatile("s_waitcnt vmcnt(0)" ::: "memory");  // drain dummy stage before LDS dealloc
  // ---- epilogue: broadcast 1/l (q-col layout) to crow layout via wave-private LDS ----
  Sc[wave][l31]      = 1.0f / lA;
  Sc[wave][32 + l31] = 1.0f / lB;
#pragma unroll
  for (int bq = 0; bq < 4; ++bq) {
    f32x4 i0 = *(const f32x4*)&Sc[wave][bq*8 + hi*4];
    f32x4 i1 = *(const f32x4*)&Sc[wave][32 + bq*8 + hi*4];
#pragma unroll
    for (int a = 0; a < 4; ++a) {
      int ql = 8*bq + 4*hi + a, r = bq*4 + a;   // q_local = (r&3) + 8*(r>>2) + 4*hi
      int sA_ = qbase + ql;
      size_t ob0 = ((size_t)(b * S_ + sA_) * NH_ + h) * HD_;
      ctx16[ob0 + l31]      = f2bf(O00[r] * i0[a]);
      ctx16[ob0 + 32 + l31] = f2bf(O01[r] * i0[a]);
      int sB_ = qbase + 32 + ql;
      size_t ob1 = ((size_t)(b * S_ + sB_) * NH_ + h) * HD_;
      ctx16[ob1 + l31]      = f2bf(O10[r] * i1[a]);
      ctx16[ob1 + 32 + l31] = f2bf(O11[r] * i1[a]);
    }
  }
#undef STAGE
}

// ---------------- LayerNorm (in-place on d_out) ----------------

__global__ __launch_bounds__(256) void ln_kernel(float* __restrict__ x, const float* __restrict__ g,
                                                 const float* __restrict__ bb) {
  const int row = blockIdx.x, t = threadIdx.x;
  float* xr = x + (size_t)row * H_;
  f32x4 v = ((const f32x4*)xr)[t];
  float s = v.x + v.y + v.z + v.w;
  float s2 = v.x*v.x + v.y*v.y + v.z*v.z + v.w*v.w;
#pragma unroll
  for (int o = 1; o < 64; o <<= 1) { s += __shfl_xor(s, o, 64); s2 += __shfl_xor(s2, o, 64); }
  __shared__ float red[8];
  const int wave = t >> 6, lane = t & 63;
  if (lane == 0) { red[wave] = s; red[4 + wave] = s2; }
  __syncthreads();
  s = red[0] + red[1] + red[2] + red[3];
  s2 = red[4] + red[5] + red[6] + red[7];
  const float mu = s * (1.0f / H_);
  const float var = s2 * (1.0f / H_) - mu * mu;
  const float rs = rsqrtf(var + 1e-12f);
  f32x4 gg = ((const f32x4*)g)[t], bb4 = ((const f32x4*)bb)[t];
  f32x4 o;
  o.x = (v.x - mu) * rs * gg.x + bb4.x;
  o.y = (v.y - mu) * rs * gg.y + bb4.y;
  o.z = (v.z - mu) * rs * gg.z + bb4.z;
  o.w = (v.w - mu) * rs * gg.w + bb4.w;
  ((f32x4*)xr)[t] = o;
}

// ---------------- launch ----------------

extern "C" void kernel_launch(void* const* d_in, const int* in_sizes, int n_in,
                              void* d_out, int out_size, void* d_ws, size_t ws_size,
                              hipStream_t stream) {
  (void)in_sizes; (void)n_in; (void)out_size; (void)ws_size;
  const float* hs   = (const float*)d_in[0];
  const float* mask = (const float*)d_in[1];
  const float* Wq = (const float*)d_in[2];
  const float* bq = (const float*)d_in[3];
  const float* Wk = (const float*)d_in[4];
  const float* bk = (const float*)d_in[5];
  const float* Wv = (const float*)d_in[6];
  const float* bv = (const float*)d_in[7];
  const float* Wo = (const float*)d_in[8];
  const float* bo = (const float*)d_in[9];
  const float* lg = (const float*)d_in[10];
  const float* lb = (const float*)d_in[11];
  float* out = (float*)d_out;

  uint8_t* w = (uint8_t*)d_ws;
  u16* hs16  = (u16*)w;                                 // 16 MB: (M,H) bf16
  u16* wt16  = (u16*)(w + ((size_t)16 << 20));          //  8 MB: 4x (N,K) bf16 W^T
  u16* qkv16 = (u16*)(w + ((size_t)24 << 20));          // 48 MB: Q,K [b][h][s][d]; V [b][h][d][s]
  u16* ctx16 = (u16*)(w + ((size_t)72 << 20));          // 16 MB: (M,H) bf16
  float* madd_g = (float*)(w + ((size_t)88 << 20));     // 32 KB: (B,S) mask add
  uint32_t* nzbits = (uint32_t*)(w + ((size_t)88 << 20) + 32768);  // 16 B

  const size_t psz = (size_t)B_*NH_*S_*HD_;
  prep_kernel<<<dim3(5124), dim3(256), 0, stream>>>(hs, hs16, mask, madd_g, nzbits,
                                                    Wq, Wk, Wv, Wo, wt16);
  gemm_qkv_kernel<<<dim3(1536), dim3(256), 0, stream>>>(hs16, wt16, bq, bk, bv, qkv16);
  attn_kernel<<<dim3(512), dim3(256), 0, stream>>>(qkv16, qkv16 + psz, qkv16 + 2*psz, madd_g, nzbits, ctx16);
  gemm_out_kernel<<<dim3(512), dim3(256), 0, stream>>>(ctx16, wt16 + (size_t)3*H_*H_, bo, hs, out);
  ln_kernel<<<dim3(M_), dim3(256), 0, stream>>>(out, lg, lb);
}

// Round 17
// 206.428 us; speedup vs baseline: 1.2452x; 1.2452x over previous
//
#include <hip/hip_runtime.h>
#include <stdint.h>

#define H_ 1024
#define NH_ 16
#define HD_ 64
#define B_ 4
#define S_ 2048
#define M_ (B_*S_)

typedef unsigned short u16;
typedef __attribute__((ext_vector_type(4))) unsigned short u16x4;
typedef __attribute__((ext_vector_type(8))) short bf16x8;
typedef __attribute__((ext_vector_type(4))) float f32x4;
typedef __attribute__((ext_vector_type(16))) float f32x16;
typedef __attribute__((ext_vector_type(4))) unsigned int u32x4;
typedef __attribute__((ext_vector_type(4))) int i32x4;

#define AS1 __attribute__((address_space(1)))
#define AS3 __attribute__((address_space(3)))

__device__ __forceinline__ void gload16(const void* g, void* l) {
  __builtin_amdgcn_global_load_lds((const AS1 void*)g, (AS3 void*)l, 16, 0, 0);
}

__device__ __forceinline__ u16 f2bf(float f) {
  union { float f; uint32_t u; } v; v.f = f;
  uint32_t u = v.u + 0x7FFFu + ((v.u >> 16) & 1u);
  return (u16)(u >> 16);
}

static __device__ __forceinline__ f32x4 mfma16(bf16x8 a, bf16x8 b, f32x4 c) {
  return __builtin_amdgcn_mfma_f32_16x16x32_bf16(a, b, c, 0, 0, 0);
}
static __device__ __forceinline__ f32x16 mfma32(bf16x8 a, bf16x8 b, f32x16 c) {
  return __builtin_amdgcn_mfma_f32_32x32x16_bf16(a, b, c, 0, 0, 0);
}

__device__ __forceinline__ int cvtpk(float lo, float hi) {
  int r;
  asm("v_cvt_pk_bf16_f32 %0, %1, %2" : "=v"(r) : "v"(lo), "v"(hi));
  return r;
}
__device__ __forceinline__ void plswap(int& a, int& b) {
  asm volatile("v_permlane32_swap_b32 %0, %1" : "+v"(a), "+v"(b));
}
#if __has_builtin(__builtin_amdgcn_exp2f)
#define EXP2F __builtin_amdgcn_exp2f
#else
#define EXP2F exp2f
#endif

// hw blockIdx -> logical id, grouping logical-contiguous blocks on one XCD (nwg%8==0)
__device__ __forceinline__ int xcd_swz(int bid, int nwg) {
  return (bid & 7) * (nwg >> 3) + (bid >> 3);
}

// ---------------- merged prep: hs->bf16 | mask->madd+bitmap | W->W^T bf16 ----------------
// bid ranges: [0,4096) hs cvt; [4096,4100) mask; [4100,5124) weight transpose.

__global__ __launch_bounds__(256) void prep_kernel(const float* __restrict__ in, u16* __restrict__ out,
                                                   const float* __restrict__ mask, float* __restrict__ madd_g,
                                                   uint32_t* __restrict__ nzbits,
                                                   const float* __restrict__ Wq, const float* __restrict__ Wk,
                                                   const float* __restrict__ Wv, const float* __restrict__ Wo,
                                                   u16* __restrict__ wt) {
  __shared__ float tile[64][65];
  const int bid = blockIdx.x, t = threadIdx.x;
  if (bid < 4096) {
    int i = bid * 256 + t;   // each thread: 8 elems
    const f32x4* p = (const f32x4*)in;
    f32x4 a = p[2*i], b = p[2*i+1];
    u32x4 o;
    o.x = (uint32_t)f2bf(a.x) | ((uint32_t)f2bf(a.y) << 16);
    o.y = (uint32_t)f2bf(a.z) | ((uint32_t)f2bf(a.w) << 16);
    o.z = (uint32_t)f2bf(b.x) | ((uint32_t)f2bf(b.y) << 16);
    o.w = (uint32_t)f2bf(b.z) | ((uint32_t)f2bf(b.w) << 16);
    ((u32x4*)out)[i] = o;
  } else if (bid < 4100) {
    const int mb = bid - 4096;                // 0..3
    int i = mb * 256 + t;                     // 1024 threads x 8 = 8192 mask elems
    f32x4 a = ((const f32x4*)mask)[2*i], b4 = ((const f32x4*)mask)[2*i+1];
    f32x4 ma, mb4;
    ma.x = (1.0f - a.x) * -3.0e38f;  ma.y = (1.0f - a.y) * -3.0e38f;
    ma.z = (1.0f - a.z) * -3.0e38f;  ma.w = (1.0f - a.w) * -3.0e38f;
    mb4.x = (1.0f - b4.x) * -3.0e38f; mb4.y = (1.0f - b4.y) * -3.0e38f;
    mb4.z = (1.0f - b4.z) * -3.0e38f; mb4.w = (1.0f - b4.w) * -3.0e38f;
    ((f32x4*)madd_g)[2*i] = ma;  ((f32x4*)madd_g)[2*i+1] = mb4;
    if (mb == 0) {  // per-(b, kv-tile) nonzero flags
      if (t < B_) nzbits[t] = 0u;
      __syncthreads();
      if (t < B_*32) {
        int b = t >> 5, kt = t & 31;
        const float* mrow = mask + (size_t)b * S_ + kt*64;
        uint32_t nz = 0;
        for (int c = 0; c < 64; ++c) nz |= (mrow[c] != 1.0f) ? 1u : 0u;
        if (nz) atomicOr(&nzbits[b], 1u << kt);
      }
    }
  } else {
    const int w = bid - 4100;                 // 0..1023
    const int p = w >> 8, ti = w & 255, tr = ti >> 4, tc = ti & 15;
    const float* W = (p == 0) ? Wq : (p == 1) ? Wk : (p == 2) ? Wv : Wo;
#pragma unroll
    for (int it = 0; it < 16; ++it) {
      int idx = it * 256 + t, r = idx >> 6, c = idx & 63;
      tile[r][c] = W[(size_t)(tr*64 + r) * H_ + tc*64 + c];
    }
    __syncthreads();
    u16* outp = wt + (size_t)p * H_ * H_;
#pragma unroll
    for (int it = 0; it < 16; ++it) {
      int idx = it * 256 + t, r = idx >> 6, c = idx & 63;
      outp[(size_t)(tc*64 + r) * H_ + tr*64 + c] = f2bf(tile[c][r]);
    }
  }
}

// ---------------- GEMM (R12 exact): 128x128 block, wave tile 64x64, BK=32, dbuf ------
// Linear [128][32] LDS (64B rows -> 2-way-max conflicts, free). Double-buffered
// global_load_lds with counted vmcnt(4) + raw s_barrier (no vmcnt(0) drain in loop).

__device__ __forceinline__ void gemm_tile(const u16* __restrict__ A, const u16* __restrict__ Bt,
                                          int m0, int n0, u16* As, u16* Bs, f32x4 acc[4][4]) {
  const int tid = threadIdx.x;
  const int lane = tid & 63, wave = tid >> 6;
  const int wr = wave >> 1, wc = wave & 1;
  const int l15 = lane & 15, l4 = lane >> 4;
  const int r0 = tid >> 2, c0 = (tid & 3) * 8;
  const u16* Ap0 = A + (size_t)(m0 + r0) * H_ + c0;
  const u16* Ap1 = A + (size_t)(m0 + 64 + r0) * H_ + c0;
  const u16* Bp0 = Bt + (size_t)(n0 + r0) * H_ + c0;
  const u16* Bp1 = Bt + (size_t)(n0 + 64 + r0) * H_ + c0;
#define GSTAGE(bb, k0) do { \
    gload16(Ap0 + (k0), As + (bb)*4096 + (size_t)tid * 8); \
    gload16(Ap1 + (k0), As + (bb)*4096 + 2048 + (size_t)tid * 8); \
    gload16(Bp0 + (k0), Bs + (bb)*4096 + (size_t)tid * 8); \
    gload16(Bp1 + (k0), Bs + (bb)*4096 + 2048 + (size_t)tid * 8); \
  } while (0)
  GSTAGE(0, 0);
  for (int kt = 0; kt < 32; ++kt) {
    const int cur = kt & 1;
    const int nk = ((kt + 1) & 31) * 32;    // kt=31: dummy restage of k=0 keeps vmcnt uniform
    GSTAGE(cur ^ 1, nk);
    asm volatile("s_waitcnt vmcnt(4)\n\ts_barrier" ::: "memory");  // cur buffer complete
    const u16* Ab = As + cur*4096;
    const u16* Bb = Bs + cur*4096;
    bf16x8 afr[4], bfr[4];
#pragma unroll
    for (int m = 0; m < 4; ++m) afr[m] = *(const bf16x8*)&Ab[(wr*64 + m*16 + l15) * 32 + l4*8];
#pragma unroll
    for (int n = 0; n < 4; ++n) bfr[n] = *(const bf16x8*)&Bb[(wc*64 + n*16 + l15) * 32 + l4*8];
#pragma unroll
    for (int m = 0; m < 4; ++m)
#pragma unroll
      for (int n = 0; n < 4; ++n)
        acc[m][n] = mfma16(afr[m], bfr[n], acc[m][n]);
    asm volatile("s_barrier" ::: "memory");  // all waves done reading buf[cur] before re-stage
  }
  asm volatile("s_waitcnt vmcnt(0)" ::: "memory");   // drain dummy stage
#undef GSTAGE
}

// QKV: C (8192 x 3072). Q (prescaled by 0.125*log2e), K -> [b][h][s][d]; V -> [b][h][d][s]
// 2D XCD chunk map: each XCD owns a fixed 3-col B stripe (768KB, L2-resident) and
// streams A in 8-panel (2MB) chunks. Bijective: bid = (cm*24 + mi*3 + ni)*8 + xcd.
__global__ __launch_bounds__(256) void gemm_qkv_kernel(const u16* __restrict__ hs16, const u16* __restrict__ wt,
                                                       const float* __restrict__ bq, const float* __restrict__ bk,
                                                       const float* __restrict__ bv, u16* __restrict__ qkv16) {
  __shared__ __align__(16) u16 As[2*128*32], Bs[2*128*32];
  f32x4 acc[4][4] = {};
  const int xcd = blockIdx.x & 7, r = blockIdx.x >> 3;      // r in 0..191
  const int cm = r / 24, idx = r % 24;                      // 8 chunks of 8m x 3n
  const int mi = idx / 3, ni = idx % 3;
  const int m0 = (cm*8 + mi) * 128, n0 = (xcd*3 + ni) * 128;
  gemm_tile(hs16, wt, m0, n0, As, Bs, acc);
  const int tid = threadIdx.x, lane = tid & 63, wave = tid >> 6;
  const int wr = wave >> 1, wc = wave & 1, l15 = lane & 15, l4 = lane >> 4;
  const int p = n0 >> 10;
  const float* bias = (p == 0) ? bq : (p == 1) ? bk : bv;
  const float qsc = (p == 0) ? 0.18033688f : 1.0f;   // 0.125 * log2(e)
  u16* base = qkv16 + (size_t)p * ((size_t)B_*NH_*S_*HD_);
  if (p == 2) {
    const int b = m0 >> 11;
#pragma unroll
    for (int n = 0; n < 4; ++n) {
      int ncol = (n0 & 1023) + wc*64 + n*16 + l15;
      int h = ncol >> 6, d = ncol & 63;
      float bsv = bias[ncol];
#pragma unroll
      for (int m = 0; m < 4; ++m) {
        int s0 = (m0 & 2047) + wr*64 + m*16 + l4*4;
        u16x4 pk;
#pragma unroll
        for (int rr = 0; rr < 4; ++rr) pk[rr] = f2bf(acc[m][n][rr] + bsv);
        *(u16x4*)(base + (((size_t)b*NH_ + h)*HD_ + d)*S_ + s0) = pk;
      }
    }
  } else {
#pragma unroll
    for (int n = 0; n < 4; ++n) {
      int ncol = (n0 & 1023) + wc*64 + n*16 + l15;
      int h = ncol >> 6, d = ncol & 63;
      float bsv = bias[ncol];
#pragma unroll
      for (int m = 0; m < 4; ++m) {
#pragma unroll
        for (int rr = 0; rr < 4; ++rr) {
          int row = m0 + wr*64 + m*16 + l4*4 + rr;
          int b = row >> 11, s = row & 2047;
          base[(((size_t)b*NH_ + h)*S_ + s)*HD_ + d] = f2bf((acc[m][n][rr] + bsv) * qsc);
        }
      }
    }
  }
}

// out-proj: C = ctx16 @ Wo + bo + residual(hs) -> fp32 xout
// 2D XCD chunk map: each XCD owns one 128-col B stripe (256KB, L2-resident).
__global__ __launch_bounds__(256) void gemm_out_kernel(const u16* __restrict__ ctx16, const u16* __restrict__ wo,
                                                       const float* __restrict__ bo, const float* __restrict__ hs,
                                                       float* __restrict__ xout) {
  __shared__ __align__(16) u16 As[2*128*32], Bs[2*128*32];
  f32x4 acc[4][4] = {};
  const int xcd = blockIdx.x & 7, r = blockIdx.x >> 3;      // r in 0..63
  const int m0 = r * 128, n0 = xcd * 128;
  gemm_tile(ctx16, wo, m0, n0, As, Bs, acc);
  const int tid = threadIdx.x, lane = tid & 63, wave = tid >> 6;
  const int wr = wave >> 1, wc = wave & 1, l15 = lane & 15, l4 = lane >> 4;
#pragma unroll
  for (int n = 0; n < 4; ++n) {
    int col = n0 + wc*64 + n*16 + l15;
    float bsv = bo[col];
#pragma unroll
    for (int m = 0; m < 4; ++m) {
#pragma unroll
      for (int rr = 0; rr < 4; ++rr) {
        int row = m0 + wr*64 + m*16 + l4*4 + rr;
        size_t off = (size_t)row * H_ + col;
        xout[off] = acc[m][n][rr] + bsv + hs[off];
      }
    }
  }
}

// ---------------- flash attention (R12 exact): 4 waves x 64 q-rows, chainless softmax --
// 2-deep staging (vmcnt(4)), raw exp2, VALU l-sum, epilogue Sc broadcast.

__global__ __launch_bounds__(256, 2) void attn_kernel(const u16* __restrict__ q_, const u16* __restrict__ k_,
                                                      const u16* __restrict__ vt_, const float* __restrict__ madd_g,
                                                      const uint32_t* __restrict__ nzbits,
                                                      u16* __restrict__ ctx16) {
  __shared__ __align__(16) u16 Ks[2][64*64], Vs[2][64*64];
  __shared__ __align__(16) float Sc[4][64];
  const int lgid = xcd_swz(blockIdx.x, 512);
  const int qb = lgid & 7, bh = lgid >> 3, h = bh & 15, b = bh >> 4;
  const int tid = threadIdx.x, lane = tid & 63, wave = tid >> 6;
  const int l31 = lane & 31, hi = lane >> 5;
  const size_t headoff = ((size_t)b * NH_ + h) * ((size_t)S_ * HD_);
  const u16* Q  = q_ + headoff;
  const u16* K  = k_ + headoff;
  const u16* Vt = vt_ + headoff;     // [d][s]
  const uint32_t nzb = nzbits[b];
  const int qbase = qb*256 + wave*64;
  bf16x8 qfA[4], qfB[4];             // strip A rows qbase+l31, strip B rows qbase+32+l31
#pragma unroll
  for (int st = 0; st < 4; ++st) {
    qfA[st] = *(const bf16x8*)(Q + (size_t)(qbase + l31) * HD_ + st*16 + hi*8);
    qfB[st] = *(const bf16x8*)(Q + (size_t)(qbase + 32 + l31) * HD_ + st*16 + hi*8);
  }
  f32x16 O00 = {}, O01 = {}, O10 = {}, O11 = {};
  float lA = 0.f, lB = 0.f;
  const int srow = tid >> 3, sch = tid & 7;
  const int gch = sch ^ (srow & 7);           // inverse-XOR source chunk (involution)
  const int swzA = l31 & 7;                   // read-side row&7

#define STAGE(bb, kt) do { \
    const u16* Kt_ = K + (size_t)(kt) * 64 * HD_; \
    _Pragma("unroll") \
    for (int c = 0; c < 2; ++c) { \
      int row = c*32 + srow; \
      gload16(Kt_ + (size_t)row * HD_ + gch*8, &Ks[bb][c*2048 + (size_t)tid*8]); \
      gload16(Vt + (size_t)row * S_ + (kt)*64 + gch*8, &Vs[bb][c*2048 + (size_t)tid*8]); \
    } \
  } while (0)

  STAGE(0, 0);
  __syncthreads();   // prologue full drain: tile 0 staged

  for (int kt = 0; kt < 32; ++kt) {
    const int cur = kt & 1;
    const int nxt = (kt + 1) & 31;  // kt=31 stages a dummy (tile 0) to keep vmcnt uniform
    STAGE(cur ^ 1, nxt);
    asm volatile("s_waitcnt vmcnt(4)\n\ts_barrier" ::: "memory");
    // ---- QK^T: S^T[kv][q] for both strips; K frags shared ----
    f32x16 sA0 = {}, sA1 = {}, sB0 = {}, sB1 = {};
    __builtin_amdgcn_s_setprio(1);
#pragma unroll
    for (int st = 0; st < 4; ++st) {
      const int kch = ((2*st + hi) ^ swzA) * 8;
      bf16x8 kf0 = *(const bf16x8*)&Ks[cur][l31*64 + kch];
      bf16x8 kf1 = *(const bf16x8*)&Ks[cur][(32 + l31)*64 + kch];
      sA0 = mfma32(kf0, qfA[st], sA0);
      sA1 = mfma32(kf1, qfA[st], sA1);
      sB0 = mfma32(kf0, qfB[st], sB0);
      sB1 = mfma32(kf1, qfB[st], sB1);
    }
    __builtin_amdgcn_s_setprio(0);
    // ---- mask add (rare path), then raw exp2 (no max subtraction) ----
    if ((nzb >> kt) & 1u) {
#pragma unroll
      for (int t = 0; t < 2; ++t) {
        f32x16& sa = t ? sA1 : sA0;
        f32x16& sb2 = t ? sB1 : sB0;
#pragma unroll
        for (int bq = 0; bq < 4; ++bq) {
          f32x4 md = *(const f32x4*)(madd_g + (size_t)b * S_ + kt*64 + t*32 + bq*8 + hi*4);
#pragma unroll
          for (int a = 0; a < 4; ++a) { sa[bq*4 + a] += md[a]; sb2[bq*4 + a] += md[a]; }
        }
      }
    }
#pragma unroll
    for (int r = 0; r < 16; ++r) sA0[r] = EXP2F(sA0[r]);
#pragma unroll
    for (int r = 0; r < 16; ++r) sA1[r] = EXP2F(sA1[r]);
#pragma unroll
    for (int r = 0; r < 16; ++r) sB0[r] = EXP2F(sB0[r]);
#pragma unroll
    for (int r = 0; r < 16; ++r) sB1[r] = EXP2F(sB1[r]);
    // ---- l via in-register add tree (independent of PV; epilogue-only consumer) ----
    {
      float v[16];
#pragma unroll
      for (int r = 0; r < 16; ++r) v[r] = sA0[r] + sA1[r];
#pragma unroll
      for (int r = 0; r < 8; ++r) v[r] += v[r+8];
#pragma unroll
      for (int r = 0; r < 4; ++r) v[r] += v[r+4];
      float rs_ = (v[0] + v[1]) + (v[2] + v[3]);
      int a0 = __float_as_int(rs_), b0 = a0; plswap(a0, b0);
      lA += __int_as_float(a0) + __int_as_float(b0);
#pragma unroll
      for (int r = 0; r < 16; ++r) v[r] = sB0[r] + sB1[r];
#pragma unroll
      for (int r = 0; r < 8; ++r) v[r] += v[r+8];
#pragma unroll
      for (int r = 0; r < 4; ++r) v[r] += v[r+4];
      rs_ = (v[0] + v[1]) + (v[2] + v[3]);
      int a1 = __float_as_int(rs_), b1 = a1; plswap(a1, b1);
      lB += __int_as_float(a1) + __int_as_float(b1);
    }
    // ---- pack P -> bf16 frags (cvt_pk + permlane32_swap); PV; V frags shared ----
    __builtin_amdgcn_s_setprio(1);
#pragma unroll
    for (int ks = 0; ks < 4; ++ks) {
      const f32x16& sa = (ks < 2) ? sA0 : sA1;
      const f32x16& sb2 = (ks < 2) ? sB0 : sB1;
      const int p = ks & 1;
      int pa0 = cvtpk(sa[8*p+0], sa[8*p+1]);
      int pa1 = cvtpk(sa[8*p+2], sa[8*p+3]);
      int pa2 = cvtpk(sa[8*p+4], sa[8*p+5]);
      int pa3 = cvtpk(sa[8*p+6], sa[8*p+7]);
      plswap(pa0, pa2); plswap(pa1, pa3);
      union { i32x4 i; bf16x8 hv; } ua; ua.i = (i32x4){pa0, pa1, pa2, pa3};
      int pb0 = cvtpk(sb2[8*p+0], sb2[8*p+1]);
      int pb1 = cvtpk(sb2[8*p+2], sb2[8*p+3]);
      int pb2 = cvtpk(sb2[8*p+4], sb2[8*p+5]);
      int pb3 = cvtpk(sb2[8*p+6], sb2[8*p+7]);
      plswap(pb0, pb2); plswap(pb1, pb3);
      union { i32x4 i; bf16x8 hv; } ub; ub.i = (i32x4){pb0, pb1, pb2, pb3};
      const int vch = ((2*ks + hi) ^ swzA) * 8;
      bf16x8 vb0 = *(const bf16x8*)&Vs[cur][l31*64 + vch];
      bf16x8 vb1 = *(const bf16x8*)&Vs[cur][(32 + l31)*64 + vch];
      O00 = mfma32(ua.hv, vb0, O00);
      O01 = mfma32(ua.hv, vb1, O01);
      O10 = mfma32(ub.hv, vb0, O10);
      O11 = mfma32(ub.hv, vb1, O11);
    }
    __builtin_amdgcn_s_setprio(0);
    asm volatile("s_barrier" ::: "memory");  // all waves done reading buf[cur]
  }
  asm volatile("s_waitcnt vmcnt(0)" ::: "memory");  // drain dummy stage before LDS dealloc
  // ---- epilogue: broadcast 1/l (q-col layout) to crow layout via wave-private LDS ----
  Sc[wave][l31]      = 1.0f / lA;
  Sc[wave][32 + l31] = 1.0f / lB;
#pragma unroll
  for (int bq = 0; bq < 4; ++bq) {
    f32x4 i0 = *(const f32x4*)&Sc[wave][bq*8 + hi*4];
    f32x4 i1 = *(const f32x4*)&Sc[wave][32 + bq*8 + hi*4];
#pragma unroll
    for (int a = 0; a < 4; ++a) {
      int ql = 8*bq + 4*hi + a, r = bq*4 + a;   // q_local = (r&3) + 8*(r>>2) + 4*hi
      int sA_ = qbase + ql;
      size_t ob0 = ((size_t)(b * S_ + sA_) * NH_ + h) * HD_;
      ctx16[ob0 + l31]      = f2bf(O00[r] * i0[a]);
      ctx16[ob0 + 32 + l31] = f2bf(O01[r] * i0[a]);
      int sB_ = qbase + 32 + ql;
      size_t ob1 = ((size_t)(b * S_ + sB_) * NH_ + h) * HD_;
      ctx16[ob1 + l31]      = f2bf(O10[r] * i1[a]);
      ctx16[ob1 + 32 + l31] = f2bf(O11[r] * i1[a]);
    }
  }
#undef STAGE
}

// ---------------- LayerNorm (in-place on d_out) ----------------

__global__ __launch_bounds__(256) void ln_kernel(float* __restrict__ x, const float* __restrict__ g,
                                                 const float* __restrict__ bb) {
  const int row = blockIdx.x, t = threadIdx.x;
  float* xr = x + (size_t)row * H_;
  f32x4 v = ((const f32x4*)xr)[t];
  float s = v.x + v.y + v.z + v.w;
  float s2 = v.x*v.x + v.y*v.y + v.z*v.z + v.w*v.w;
#pragma unroll
  for (int o = 1; o < 64; o <<= 1) { s += __shfl_xor(s, o, 64); s2 += __shfl_xor(s2, o, 64); }
  __shared__ float red[8];
  const int wave = t >> 6, lane = t & 63;
  if (lane == 0) { red[wave] = s; red[4 + wave] = s2; }
  __syncthreads();
  s = red[0] + red[1] + red[2] + red[3];
  s2 = red[4] + red[5] + red[6] + red[7];
  const float mu = s * (1.0f / H_);
  const float var = s2 * (1.0f / H_) - mu * mu;
  const float rs = rsqrtf(var + 1e-12f);
  f32x4 gg = ((const f32x4*)g)[t], bb4 = ((const f32x4*)bb)[t];
  f32x4 o;
  o.x = (v.x - mu) * rs * gg.x + bb4.x;
  o.y = (v.y - mu) * rs * gg.y + bb4.y;
  o.z = (v.z - mu) * rs * gg.z + bb4.z;
  o.w = (v.w - mu) * rs * gg.w + bb4.w;
  ((f32x4*)xr)[t] = o;
}

// ---------------- launch ----------------

extern "C" void kernel_launch(void* const* d_in, const int* in_sizes, int n_in,
                              void* d_out, int out_size, void* d_ws, size_t ws_size,
                              hipStream_t stream) {
  (void)in_sizes; (void)n_in; (void)out_size; (void)ws_size;
  const float* hs   = (const float*)d_in[0];
  const float* mask = (const float*)d_in[1];
  const float* Wq = (const float*)d_in[2];
  const float* bq = (const float*)d_in[3];
  const float* Wk = (const float*)d_in[4];
  const float* bk = (const float*)d_in[5];
  const float* Wv = (const float*)d_in[6];
  const float* bv = (const float*)d_in[7];
  const float* Wo = (const float*)d_in[8];
  const float* bo = (const float*)d_in[9];
  const float* lg = (const float*)d_in[10];
  const float* lb = (const float*)d_in[11];
  float* out = (float*)d_out;

  uint8_t* w = (uint8_t*)d_ws;
  u16* hs16  = (u16*)w;                                 // 16 MB: (M,H) bf16
  u16* wt16  = (u16*)(w + ((size_t)16 << 20));          //  8 MB: 4x (N,K) bf16 W^T
  u16* qkv16 = (u16*)(w + ((size_t)24 << 20));          // 48 MB: Q,K [b][h][s][d]; V [b][h][d][s]
  u16* ctx16 = (u16*)(w + ((size_t)72 << 20));          // 16 MB: (M,H) bf16
  float* madd_g = (float*)(w + ((size_t)88 << 20));     // 32 KB: (B,S) mask add
  uint32_t* nzbits = (uint32_t*)(w + ((size_t)88 << 20) + 32768);  // 16 B

  const size_t psz = (size_t)B_*NH_*S_*HD_;
  prep_kernel<<<dim3(5124), dim3(256), 0, stream>>>(hs, hs16, mask, madd_g, nzbits,
                                                    Wq, Wk, Wv, Wo, wt16);
  gemm_qkv_kernel<<<dim3(1536), dim3(256), 0, stream>>>(hs16, wt16, bq, bk, bv, qkv16);
  attn_kernel<<<dim3(512), dim3(256), 0, stream>>>(qkv16, qkv16 + psz, qkv16 + 2*psz, madd_g, nzbits, ctx16);
  gemm_out_kernel<<<dim3(512), dim3(256), 0, stream>>>(ctx16, wt16 + (size_t)3*H_*H_, bo, hs, out);
  ln_kernel<<<dim3(M_), dim3(256), 0, stream>>>(out, lg, lb);
}

// Round 18
// 199.827 us; speedup vs baseline: 1.2863x; 1.0330x over previous
//
#include <hip/hip_runtime.h>
#include <stdint.h>

#define H_ 1024
#define NH_ 16
#define HD_ 64
#define B_ 4
#define S_ 2048
#define M_ (B_*S_)

typedef unsigned short u16;
typedef __attribute__((ext_vector_type(4))) unsigned short u16x4;
typedef __attribute__((ext_vector_type(8))) short bf16x8;
typedef __attribute__((ext_vector_type(4))) float f32x4;
typedef __attribute__((ext_vector_type(16))) float f32x16;
typedef __attribute__((ext_vector_type(4))) unsigned int u32x4;
typedef __attribute__((ext_vector_type(4))) int i32x4;

#define AS1 __attribute__((address_space(1)))
#define AS3 __attribute__((address_space(3)))

__device__ __forceinline__ void gload16(const void* g, void* l) {
  __builtin_amdgcn_global_load_lds((const AS1 void*)g, (AS3 void*)l, 16, 0, 0);
}

__device__ __forceinline__ u16 f2bf(float f) {
  union { float f; uint32_t u; } v; v.f = f;
  uint32_t u = v.u + 0x7FFFu + ((v.u >> 16) & 1u);
  return (u16)(u >> 16);
}

static __device__ __forceinline__ f32x4 mfma16(bf16x8 a, bf16x8 b, f32x4 c) {
  return __builtin_amdgcn_mfma_f32_16x16x32_bf16(a, b, c, 0, 0, 0);
}
static __device__ __forceinline__ f32x16 mfma32(bf16x8 a, bf16x8 b, f32x16 c) {
  return __builtin_amdgcn_mfma_f32_32x32x16_bf16(a, b, c, 0, 0, 0);
}

__device__ __forceinline__ int cvtpk(float lo, float hi) {
  int r;
  asm("v_cvt_pk_bf16_f32 %0, %1, %2" : "=v"(r) : "v"(lo), "v"(hi));
  return r;
}
__device__ __forceinline__ void plswap(int& a, int& b) {
  asm volatile("v_permlane32_swap_b32 %0, %1" : "+v"(a), "+v"(b));
}
#if __has_builtin(__builtin_amdgcn_exp2f)
#define EXP2F __builtin_amdgcn_exp2f
#else
#define EXP2F exp2f
#endif

// hw blockIdx -> logical id, grouping logical-contiguous blocks on one XCD (nwg%8==0)
__device__ __forceinline__ int xcd_swz(int bid, int nwg) {
  return (bid & 7) * (nwg >> 3) + (bid >> 3);
}

// ---------------- merged prep: hs->bf16 | mask->madd+bitmap | W->W^T bf16 ----------------
// bid ranges: [0,4096) hs cvt; [4096,4100) mask; [4100,5124) weight transpose.

__global__ __launch_bounds__(256) void prep_kernel(const float* __restrict__ in, u16* __restrict__ out,
                                                   const float* __restrict__ mask, float* __restrict__ madd_g,
                                                   uint32_t* __restrict__ nzbits,
                                                   const float* __restrict__ Wq, const float* __restrict__ Wk,
                                                   const float* __restrict__ Wv, const float* __restrict__ Wo,
                                                   u16* __restrict__ wt) {
  __shared__ float tile[64][65];
  const int bid = blockIdx.x, t = threadIdx.x;
  if (bid < 4096) {
    int i = bid * 256 + t;   // each thread: 8 elems
    const f32x4* p = (const f32x4*)in;
    f32x4 a = p[2*i], b = p[2*i+1];
    u32x4 o;
    o.x = (uint32_t)f2bf(a.x) | ((uint32_t)f2bf(a.y) << 16);
    o.y = (uint32_t)f2bf(a.z) | ((uint32_t)f2bf(a.w) << 16);
    o.z = (uint32_t)f2bf(b.x) | ((uint32_t)f2bf(b.y) << 16);
    o.w = (uint32_t)f2bf(b.z) | ((uint32_t)f2bf(b.w) << 16);
    ((u32x4*)out)[i] = o;
  } else if (bid < 4100) {
    const int mb = bid - 4096;                // 0..3
    int i = mb * 256 + t;                     // 1024 threads x 8 = 8192 mask elems
    f32x4 a = ((const f32x4*)mask)[2*i], b4 = ((const f32x4*)mask)[2*i+1];
    f32x4 ma, mb4;
    ma.x = (1.0f - a.x) * -3.0e38f;  ma.y = (1.0f - a.y) * -3.0e38f;
    ma.z = (1.0f - a.z) * -3.0e38f;  ma.w = (1.0f - a.w) * -3.0e38f;
    mb4.x = (1.0f - b4.x) * -3.0e38f; mb4.y = (1.0f - b4.y) * -3.0e38f;
    mb4.z = (1.0f - b4.z) * -3.0e38f; mb4.w = (1.0f - b4.w) * -3.0e38f;
    ((f32x4*)madd_g)[2*i] = ma;  ((f32x4*)madd_g)[2*i+1] = mb4;
    if (mb == 0) {  // per-(b, kv-tile) nonzero flags
      if (t < B_) nzbits[t] = 0u;
      __syncthreads();
      if (t < B_*32) {
        int b = t >> 5, kt = t & 31;
        const float* mrow = mask + (size_t)b * S_ + kt*64;
        uint32_t nz = 0;
        for (int c = 0; c < 64; ++c) nz |= (mrow[c] != 1.0f) ? 1u : 0u;
        if (nz) atomicOr(&nzbits[b], 1u << kt);
      }
    }
  } else {
    const int w = bid - 4100;                 // 0..1023
    const int p = w >> 8, ti = w & 255, tr = ti >> 4, tc = ti & 15;
    const float* W = (p == 0) ? Wq : (p == 1) ? Wk : (p == 2) ? Wv : Wo;
#pragma unroll
    for (int it = 0; it < 16; ++it) {
      int idx = it * 256 + t, r = idx >> 6, c = idx & 63;
      tile[r][c] = W[(size_t)(tr*64 + r) * H_ + tc*64 + c];
    }
    __syncthreads();
    u16* outp = wt + (size_t)p * H_ * H_;
#pragma unroll
    for (int it = 0; it < 16; ++it) {
      int idx = it * 256 + t, r = idx >> 6, c = idx & 63;
      outp[(size_t)(tc*64 + r) * H_ + tr*64 + c] = f2bf(tile[c][r]);
    }
  }
}

// ---------------- GEMM (R12 exact): 128x128 block, wave tile 64x64, BK=32, dbuf ------
// Linear [128][32] LDS (64B rows -> 2-way-max conflicts, free). Double-buffered
// global_load_lds with counted vmcnt(4) + raw s_barrier (no vmcnt(0) drain in loop).

__device__ __forceinline__ void gemm_tile(const u16* __restrict__ A, const u16* __restrict__ Bt,
                                          int m0, int n0, u16* As, u16* Bs, f32x4 acc[4][4]) {
  const int tid = threadIdx.x;
  const int lane = tid & 63, wave = tid >> 6;
  const int wr = wave >> 1, wc = wave & 1;
  const int l15 = lane & 15, l4 = lane >> 4;
  const int r0 = tid >> 2, c0 = (tid & 3) * 8;
  const u16* Ap0 = A + (size_t)(m0 + r0) * H_ + c0;
  const u16* Ap1 = A + (size_t)(m0 + 64 + r0) * H_ + c0;
  const u16* Bp0 = Bt + (size_t)(n0 + r0) * H_ + c0;
  const u16* Bp1 = Bt + (size_t)(n0 + 64 + r0) * H_ + c0;
#define GSTAGE(bb, k0) do { \
    gload16(Ap0 + (k0), As + (bb)*4096 + (size_t)tid * 8); \
    gload16(Ap1 + (k0), As + (bb)*4096 + 2048 + (size_t)tid * 8); \
    gload16(Bp0 + (k0), Bs + (bb)*4096 + (size_t)tid * 8); \
    gload16(Bp1 + (k0), Bs + (bb)*4096 + 2048 + (size_t)tid * 8); \
  } while (0)
  GSTAGE(0, 0);
  for (int kt = 0; kt < 32; ++kt) {
    const int cur = kt & 1;
    const int nk = ((kt + 1) & 31) * 32;    // kt=31: dummy restage of k=0 keeps vmcnt uniform
    GSTAGE(cur ^ 1, nk);
    asm volatile("s_waitcnt vmcnt(4)\n\ts_barrier" ::: "memory");  // cur buffer complete
    const u16* Ab = As + cur*4096;
    const u16* Bb = Bs + cur*4096;
    bf16x8 afr[4], bfr[4];
#pragma unroll
    for (int m = 0; m < 4; ++m) afr[m] = *(const bf16x8*)&Ab[(wr*64 + m*16 + l15) * 32 + l4*8];
#pragma unroll
    for (int n = 0; n < 4; ++n) bfr[n] = *(const bf16x8*)&Bb[(wc*64 + n*16 + l15) * 32 + l4*8];
#pragma unroll
    for (int m = 0; m < 4; ++m)
#pragma unroll
      for (int n = 0; n < 4; ++n)
        acc[m][n] = mfma16(afr[m], bfr[n], acc[m][n]);
    asm volatile("s_barrier" ::: "memory");  // all waves done reading buf[cur] before re-stage
  }
  asm volatile("s_waitcnt vmcnt(0)" ::: "memory");   // drain dummy stage
#undef GSTAGE
}

// QKV: C (8192 x 3072). Q (prescaled by 0.125*log2e), K -> [b][h][s][d]; V -> [b][h][d][s]
// with V^T stores packed u16x4 along s (r=0..3 contiguous) to cut write amplification.
__global__ __launch_bounds__(256) void gemm_qkv_kernel(const u16* __restrict__ hs16, const u16* __restrict__ wt,
                                                       const float* __restrict__ bq, const float* __restrict__ bk,
                                                       const float* __restrict__ bv, u16* __restrict__ qkv16) {
  __shared__ __align__(16) u16 As[2*128*32], Bs[2*128*32];
  f32x4 acc[4][4] = {};
  const int lg = xcd_swz(blockIdx.x, 1536);
  const int m0 = (lg / 24) * 128, n0 = (lg % 24) * 128;
  gemm_tile(hs16, wt, m0, n0, As, Bs, acc);
  const int tid = threadIdx.x, lane = tid & 63, wave = tid >> 6;
  const int wr = wave >> 1, wc = wave & 1, l15 = lane & 15, l4 = lane >> 4;
  const int p = n0 >> 10;
  const float* bias = (p == 0) ? bq : (p == 1) ? bk : bv;
  const float qsc = (p == 0) ? 0.18033688f : 1.0f;   // 0.125 * log2(e)
  u16* base = qkv16 + (size_t)p * ((size_t)B_*NH_*S_*HD_);
  if (p == 2) {
    const int b = m0 >> 11;
#pragma unroll
    for (int n = 0; n < 4; ++n) {
      int ncol = (n0 & 1023) + wc*64 + n*16 + l15;
      int h = ncol >> 6, d = ncol & 63;
      float bsv = bias[ncol];
#pragma unroll
      for (int m = 0; m < 4; ++m) {
        int s0 = (m0 & 2047) + wr*64 + m*16 + l4*4;
        u16x4 pk;
#pragma unroll
        for (int r = 0; r < 4; ++r) pk[r] = f2bf(acc[m][n][r] + bsv);
        *(u16x4*)(base + (((size_t)b*NH_ + h)*HD_ + d)*S_ + s0) = pk;
      }
    }
  } else {
#pragma unroll
    for (int n = 0; n < 4; ++n) {
      int ncol = (n0 & 1023) + wc*64 + n*16 + l15;
      int h = ncol >> 6, d = ncol & 63;
      float bsv = bias[ncol];
#pragma unroll
      for (int m = 0; m < 4; ++m) {
#pragma unroll
        for (int r = 0; r < 4; ++r) {
          int row = m0 + wr*64 + m*16 + l4*4 + r;
          int b = row >> 11, s = row & 2047;
          base[(((size_t)b*NH_ + h)*S_ + s)*HD_ + d] = f2bf((acc[m][n][r] + bsv) * qsc);
        }
      }
    }
  }
}

// out-proj: C = ctx16 @ Wo + bo + residual(hs) -> fp32 xout
__global__ __launch_bounds__(256) void gemm_out_kernel(const u16* __restrict__ ctx16, const u16* __restrict__ wo,
                                                       const float* __restrict__ bo, const float* __restrict__ hs,
                                                       float* __restrict__ xout) {
  __shared__ __align__(16) u16 As[2*128*32], Bs[2*128*32];
  f32x4 acc[4][4] = {};
  const int lg = xcd_swz(blockIdx.x, 512);
  const int m0 = (lg / 8) * 128, n0 = (lg % 8) * 128;
  gemm_tile(ctx16, wo, m0, n0, As, Bs, acc);
  const int tid = threadIdx.x, lane = tid & 63, wave = tid >> 6;
  const int wr = wave >> 1, wc = wave & 1, l15 = lane & 15, l4 = lane >> 4;
#pragma unroll
  for (int n = 0; n < 4; ++n) {
    int col = n0 + wc*64 + n*16 + l15;
    float bsv = bo[col];
#pragma unroll
    for (int m = 0; m < 4; ++m) {
#pragma unroll
      for (int r = 0; r < 4; ++r) {
        int row = m0 + wr*64 + m*16 + l4*4 + r;
        size_t off = (size_t)row * H_ + col;
        xout[off] = acc[m][n][r] + bsv + hs[off];
      }
    }
  }
}

// ---------------- flash attention (R12 exact): 4 waves x 64 q-rows, chainless softmax --
// 2-deep staging (vmcnt(4)), raw exp2, VALU l-sum, epilogue Sc broadcast.

__global__ __launch_bounds__(256, 2) void attn_kernel(const u16* __restrict__ q_, const u16* __restrict__ k_,
                                                      const u16* __restrict__ vt_, const float* __restrict__ madd_g,
                                                      const uint32_t* __restrict__ nzbits,
                                                      u16* __restrict__ ctx16) {
  __shared__ __align__(16) u16 Ks[2][64*64], Vs[2][64*64];
  __shared__ __align__(16) float Sc[4][64];
  const int lgid = xcd_swz(blockIdx.x, 512);
  const int qb = lgid & 7, bh = lgid >> 3, h = bh & 15, b = bh >> 4;
  const int tid = threadIdx.x, lane = tid & 63, wave = tid >> 6;
  const int l31 = lane & 31, hi = lane >> 5;
  const size_t headoff = ((size_t)b * NH_ + h) * ((size_t)S_ * HD_);
  const u16* Q  = q_ + headoff;
  const u16* K  = k_ + headoff;
  const u16* Vt = vt_ + headoff;     // [d][s]
  const uint32_t nzb = nzbits[b];
  const int qbase = qb*256 + wave*64;
  bf16x8 qfA[4], qfB[4];             // strip A rows qbase+l31, strip B rows qbase+32+l31
#pragma unroll
  for (int st = 0; st < 4; ++st) {
    qfA[st] = *(const bf16x8*)(Q + (size_t)(qbase + l31) * HD_ + st*16 + hi*8);
    qfB[st] = *(const bf16x8*)(Q + (size_t)(qbase + 32 + l31) * HD_ + st*16 + hi*8);
  }
  f32x16 O00 = {}, O01 = {}, O10 = {}, O11 = {};
  float lA = 0.f, lB = 0.f;
  const int srow = tid >> 3, sch = tid & 7;
  const int gch = sch ^ (srow & 7);           // inverse-XOR source chunk (involution)
  const int swzA = l31 & 7;                   // read-side row&7

#define STAGE(bb, kt) do { \
    const u16* Kt_ = K + (size_t)(kt) * 64 * HD_; \
    _Pragma("unroll") \
    for (int c = 0; c < 2; ++c) { \
      int row = c*32 + srow; \
      gload16(Kt_ + (size_t)row * HD_ + gch*8, &Ks[bb][c*2048 + (size_t)tid*8]); \
      gload16(Vt + (size_t)row * S_ + (kt)*64 + gch*8, &Vs[bb][c*2048 + (size_t)tid*8]); \
    } \
  } while (0)

  STAGE(0, 0);
  __syncthreads();   // prologue full drain: tile 0 staged

  for (int kt = 0; kt < 32; ++kt) {
    const int cur = kt & 1;
    const int nxt = (kt + 1) & 31;  // kt=31 stages a dummy (tile 0) to keep vmcnt uniform
    STAGE(cur ^ 1, nxt);
    asm volatile("s_waitcnt vmcnt(4)\n\ts_barrier" ::: "memory");
    // ---- QK^T: S^T[kv][q] for both strips; K frags shared ----
    f32x16 sA0 = {}, sA1 = {}, sB0 = {}, sB1 = {};
    __builtin_amdgcn_s_setprio(1);
#pragma unroll
    for (int st = 0; st < 4; ++st) {
      const int kch = ((2*st + hi) ^ swzA) * 8;
      bf16x8 kf0 = *(const bf16x8*)&Ks[cur][l31*64 + kch];
      bf16x8 kf1 = *(const bf16x8*)&Ks[cur][(32 + l31)*64 + kch];
      sA0 = mfma32(kf0, qfA[st], sA0);
      sA1 = mfma32(kf1, qfA[st], sA1);
      sB0 = mfma32(kf0, qfB[st], sB0);
      sB1 = mfma32(kf1, qfB[st], sB1);
    }
    __builtin_amdgcn_s_setprio(0);
    // ---- mask add (rare path), then raw exp2 (no max subtraction) ----
    if ((nzb >> kt) & 1u) {
#pragma unroll
      for (int t = 0; t < 2; ++t) {
        f32x16& sa = t ? sA1 : sA0;
        f32x16& sb2 = t ? sB1 : sB0;
#pragma unroll
        for (int bq = 0; bq < 4; ++bq) {
          f32x4 md = *(const f32x4*)(madd_g + (size_t)b * S_ + kt*64 + t*32 + bq*8 + hi*4);
#pragma unroll
          for (int a = 0; a < 4; ++a) { sa[bq*4 + a] += md[a]; sb2[bq*4 + a] += md[a]; }
        }
      }
    }
#pragma unroll
    for (int r = 0; r < 16; ++r) sA0[r] = EXP2F(sA0[r]);
#pragma unroll
    for (int r = 0; r < 16; ++r) sA1[r] = EXP2F(sA1[r]);
#pragma unroll
    for (int r = 0; r < 16; ++r) sB0[r] = EXP2F(sB0[r]);
#pragma unroll
    for (int r = 0; r < 16; ++r) sB1[r] = EXP2F(sB1[r]);
    // ---- l via in-register add tree (independent of PV; epilogue-only consumer) ----
    {
      float v[16];
#pragma unroll
      for (int r = 0; r < 16; ++r) v[r] = sA0[r] + sA1[r];
#pragma unroll
      for (int r = 0; r < 8; ++r) v[r] += v[r+8];
#pragma unroll
      for (int r = 0; r < 4; ++r) v[r] += v[r+4];
      float rs_ = (v[0] + v[1]) + (v[2] + v[3]);
      int a0 = __float_as_int(rs_), b0 = a0; plswap(a0, b0);
      lA += __int_as_float(a0) + __int_as_float(b0);
#pragma unroll
      for (int r = 0; r < 16; ++r) v[r] = sB0[r] + sB1[r];
#pragma unroll
      for (int r = 0; r < 8; ++r) v[r] += v[r+8];
#pragma unroll
      for (int r = 0; r < 4; ++r) v[r] += v[r+4];
      rs_ = (v[0] + v[1]) + (v[2] + v[3]);
      int a1 = __float_as_int(rs_), b1 = a1; plswap(a1, b1);
      lB += __int_as_float(a1) + __int_as_float(b1);
    }
    // ---- pack P -> bf16 frags (cvt_pk + permlane32_swap); PV; V frags shared ----
    __builtin_amdgcn_s_setprio(1);
#pragma unroll
    for (int ks = 0; ks < 4; ++ks) {
      const f32x16& sa = (ks < 2) ? sA0 : sA1;
      const f32x16& sb2 = (ks < 2) ? sB0 : sB1;
      const int p = ks & 1;
      int pa0 = cvtpk(sa[8*p+0], sa[8*p+1]);
      int pa1 = cvtpk(sa[8*p+2], sa[8*p+3]);
      int pa2 = cvtpk(sa[8*p+4], sa[8*p+5]);
      int pa3 = cvtpk(sa[8*p+6], sa[8*p+7]);
      plswap(pa0, pa2); plswap(pa1, pa3);
      union { i32x4 i; bf16x8 hv; } ua; ua.i = (i32x4){pa0, pa1, pa2, pa3};
      int pb0 = cvtpk(sb2[8*p+0], sb2[8*p+1]);
      int pb1 = cvtpk(sb2[8*p+2], sb2[8*p+3]);
      int pb2 = cvtpk(sb2[8*p+4], sb2[8*p+5]);
      int pb3 = cvtpk(sb2[8*p+6], sb2[8*p+7]);
      plswap(pb0, pb2); plswap(pb1, pb3);
      union { i32x4 i; bf16x8 hv; } ub; ub.i = (i32x4){pb0, pb1, pb2, pb3};
      const int vch = ((2*ks + hi) ^ swzA) * 8;
      bf16x8 vb0 = *(const bf16x8*)&Vs[cur][l31*64 + vch];
      bf16x8 vb1 = *(const bf16x8*)&Vs[cur][(32 + l31)*64 + vch];
      O00 = mfma32(ua.hv, vb0, O00);
      O01 = mfma32(ua.hv, vb1, O01);
      O10 = mfma32(ub.hv, vb0, O10);
      O11 = mfma32(ub.hv, vb1, O11);
    }
    __builtin_amdgcn_s_setprio(0);
    asm volatile("s_barrier" ::: "memory");  // all waves done reading buf[cur]
  }
  asm volatile("s_waitcnt vmcnt(0)" ::: "memory");  // drain dummy stage before LDS dealloc
  // ---- epilogue: broadcast 1/l (q-col layout) to crow layout via wave-private LDS ----
  Sc[wave][l31]      = 1.0f / lA;
  Sc[wave][32 + l31] = 1.0f / lB;
#pragma unroll
  for (int bq = 0; bq < 4; ++bq) {
    f32x4 i0 = *(const f32x4*)&Sc[wave][bq*8 + hi*4];
    f32x4 i1 = *(const f32x4*)&Sc[wave][32 + bq*8 + hi*4];
#pragma unroll
    for (int a = 0; a < 4; ++a) {
      int ql = 8*bq + 4*hi + a, r = bq*4 + a;   // q_local = (r&3) + 8*(r>>2) + 4*hi
      int sA_ = qbase + ql;
      size_t ob0 = ((size_t)(b * S_ + sA_) * NH_ + h) * HD_;
      ctx16[ob0 + l31]      = f2bf(O00[r] * i0[a]);
      ctx16[ob0 + 32 + l31] = f2bf(O01[r] * i0[a]);
      int sB_ = qbase + 32 + ql;
      size_t ob1 = ((size_t)(b * S_ + sB_) * NH_ + h) * HD_;
      ctx16[ob1 + l31]      = f2bf(O10[r] * i1[a]);
      ctx16[ob1 + 32 + l31] = f2bf(O11[r] * i1[a]);
    }
  }
#undef STAGE
}

// ---------------- LayerNorm (in-place on d_out) ----------------

__global__ __launch_bounds__(256) void ln_kernel(float* __restrict__ x, const float* __restrict__ g,
                                                 const float* __restrict__ bb) {
  const int row = blockIdx.x, t = threadIdx.x;
  float* xr = x + (size_t)row * H_;
  f32x4 v = ((const f32x4*)xr)[t];
  float s = v.x + v.y + v.z + v.w;
  float s2 = v.x*v.x + v.y*v.y + v.z*v.z + v.w*v.w;
#pragma unroll
  for (int o = 1; o < 64; o <<= 1) { s += __shfl_xor(s, o, 64); s2 += __shfl_xor(s2, o, 64); }
  __shared__ float red[8];
  const int wave = t >> 6, lane = t & 63;
  if (lane == 0) { red[wave] = s; red[4 + wave] = s2; }
  __syncthreads();
  s = red[0] + red[1] + red[2] + red[3];
  s2 = red[4] + red[5] + red[6] + red[7];
  const float mu = s * (1.0f / H_);
  const float var = s2 * (1.0f / H_) - mu * mu;
  const float rs = rsqrtf(var + 1e-12f);
  f32x4 gg = ((const f32x4*)g)[t], bb4 = ((const f32x4*)bb)[t];
  f32x4 o;
  o.x = (v.x - mu) * rs * gg.x + bb4.x;
  o.y = (v.y - mu) * rs * gg.y + bb4.y;
  o.z = (v.z - mu) * rs * gg.z + bb4.z;
  o.w = (v.w - mu) * rs * gg.w + bb4.w;
  ((f32x4*)xr)[t] = o;
}

// ---------------- launch ----------------

extern "C" void kernel_launch(void* const* d_in, const int* in_sizes, int n_in,
                              void* d_out, int out_size, void* d_ws, size_t ws_size,
                              hipStream_t stream) {
  (void)in_sizes; (void)n_in; (void)out_size; (void)ws_size;
  const float* hs   = (const float*)d_in[0];
  const float* mask = (const float*)d_in[1];
  const float* Wq = (const float*)d_in[2];
  const float* bq = (const float*)d_in[3];
  const float* Wk = (const float*)d_in[4];
  const float* bk = (const float*)d_in[5];
  const float* Wv = (const float*)d_in[6];
  const float* bv = (const float*)d_in[7];
  const float* Wo = (const float*)d_in[8];
  const float* bo = (const float*)d_in[9];
  const float* lg = (const float*)d_in[10];
  const float* lb = (const float*)d_in[11];
  float* out = (float*)d_out;

  uint8_t* w = (uint8_t*)d_ws;
  u16* hs16  = (u16*)w;                                 // 16 MB: (M,H) bf16
  u16* wt16  = (u16*)(w + ((size_t)16 << 20));          //  8 MB: 4x (N,K) bf16 W^T
  u16* qkv16 = (u16*)(w + ((size_t)24 << 20));          // 48 MB: Q,K [b][h][s][d]; V [b][h][d][s]
  u16* ctx16 = (u16*)(w + ((size_t)72 << 20));          // 16 MB: (M,H) bf16
  float* madd_g = (float*)(w + ((size_t)88 << 20));     // 32 KB: (B,S) mask add
  uint32_t* nzbits = (uint32_t*)(w + ((size_t)88 << 20) + 32768);  // 16 B

  const size_t psz = (size_t)B_*NH_*S_*HD_;
  prep_kernel<<<dim3(5124), dim3(256), 0, stream>>>(hs, hs16, mask, madd_g, nzbits,
                                                    Wq, Wk, Wv, Wo, wt16);
  gemm_qkv_kernel<<<dim3(1536), dim3(256), 0, stream>>>(hs16, wt16, bq, bk, bv, qkv16);
  attn_kernel<<<dim3(512), dim3(256), 0, stream>>>(qkv16, qkv16 + psz, qkv16 + 2*psz, madd_g, nzbits, ctx16);
  gemm_out_kernel<<<dim3(512), dim3(256), 0, stream>>>(ctx16, wt16 + (size_t)3*H_*H_, bo, hs, out);
  ln_kernel<<<dim3(M_), dim3(256), 0, stream>>>(out, lg, lb);
}

// Round 19
// 196.848 us; speedup vs baseline: 1.3058x; 1.0151x over previous
//
#include <hip/hip_runtime.h>
#include <stdint.h>

#define H_ 1024
#define NH_ 16
#define HD_ 64
#define B_ 4
#define S_ 2048
#define M_ (B_*S_)

typedef unsigned short u16;
typedef __attribute__((ext_vector_type(4))) unsigned short u16x4;
typedef __attribute__((ext_vector_type(8))) short bf16x8;
typedef __attribute__((ext_vector_type(4))) float f32x4;
typedef __attribute__((ext_vector_type(16))) float f32x16;
typedef __attribute__((ext_vector_type(4))) unsigned int u32x4;
typedef __attribute__((ext_vector_type(4))) int i32x4;

#define AS1 __attribute__((address_space(1)))
#define AS3 __attribute__((address_space(3)))

__device__ __forceinline__ void gload16(const void* g, void* l) {
  __builtin_amdgcn_global_load_lds((const AS1 void*)g, (AS3 void*)l, 16, 0, 0);
}

__device__ __forceinline__ u16 f2bf(float f) {
  union { float f; uint32_t u; } v; v.f = f;
  uint32_t u = v.u + 0x7FFFu + ((v.u >> 16) & 1u);
  return (u16)(u >> 16);
}
__device__ __forceinline__ float bf2f(u16 h) {
  union { uint32_t u; float f; } v; v.u = ((uint32_t)h) << 16; return v.f;
}

static __device__ __forceinline__ f32x4 mfma16(bf16x8 a, bf16x8 b, f32x4 c) {
  return __builtin_amdgcn_mfma_f32_16x16x32_bf16(a, b, c, 0, 0, 0);
}
static __device__ __forceinline__ f32x16 mfma32(bf16x8 a, bf16x8 b, f32x16 c) {
  return __builtin_amdgcn_mfma_f32_32x32x16_bf16(a, b, c, 0, 0, 0);
}

__device__ __forceinline__ int cvtpk(float lo, float hi) {
  int r;
  asm("v_cvt_pk_bf16_f32 %0, %1, %2" : "=v"(r) : "v"(lo), "v"(hi));
  return r;
}
__device__ __forceinline__ void plswap(int& a, int& b) {
  asm volatile("v_permlane32_swap_b32 %0, %1" : "+v"(a), "+v"(b));
}
#if __has_builtin(__builtin_amdgcn_exp2f)
#define EXP2F __builtin_amdgcn_exp2f
#else
#define EXP2F exp2f
#endif

// hw blockIdx -> logical id, grouping logical-contiguous blocks on one XCD (nwg%8==0)
__device__ __forceinline__ int xcd_swz(int bid, int nwg) {
  return (bid & 7) * (nwg >> 3) + (bid >> 3);
}

// ---------------- merged prep: hs->bf16 | mask->madd+bitmap | W->W^T bf16 ----------------
// bid ranges: [0,4096) hs cvt; [4096,4100) mask; [4100,5124) weight transpose.

__global__ __launch_bounds__(256) void prep_kernel(const float* __restrict__ in, u16* __restrict__ out,
                                                   const float* __restrict__ mask, float* __restrict__ madd_g,
                                                   uint32_t* __restrict__ nzbits,
                                                   const float* __restrict__ Wq, const float* __restrict__ Wk,
                                                   const float* __restrict__ Wv, const float* __restrict__ Wo,
                                                   u16* __restrict__ wt) {
  __shared__ float tile[64][65];
  const int bid = blockIdx.x, t = threadIdx.x;
  if (bid < 4096) {
    int i = bid * 256 + t;   // each thread: 8 elems
    const f32x4* p = (const f32x4*)in;
    f32x4 a = p[2*i], b = p[2*i+1];
    u32x4 o;
    o.x = (uint32_t)f2bf(a.x) | ((uint32_t)f2bf(a.y) << 16);
    o.y = (uint32_t)f2bf(a.z) | ((uint32_t)f2bf(a.w) << 16);
    o.z = (uint32_t)f2bf(b.x) | ((uint32_t)f2bf(b.y) << 16);
    o.w = (uint32_t)f2bf(b.z) | ((uint32_t)f2bf(b.w) << 16);
    ((u32x4*)out)[i] = o;
  } else if (bid < 4100) {
    const int mb = bid - 4096;                // 0..3
    int i = mb * 256 + t;                     // 1024 threads x 8 = 8192 mask elems
    f32x4 a = ((const f32x4*)mask)[2*i], b4 = ((const f32x4*)mask)[2*i+1];
    f32x4 ma, mb4;
    ma.x = (1.0f - a.x) * -3.0e38f;  ma.y = (1.0f - a.y) * -3.0e38f;
    ma.z = (1.0f - a.z) * -3.0e38f;  ma.w = (1.0f - a.w) * -3.0e38f;
    mb4.x = (1.0f - b4.x) * -3.0e38f; mb4.y = (1.0f - b4.y) * -3.0e38f;
    mb4.z = (1.0f - b4.z) * -3.0e38f; mb4.w = (1.0f - b4.w) * -3.0e38f;
    ((f32x4*)madd_g)[2*i] = ma;  ((f32x4*)madd_g)[2*i+1] = mb4;
    if (mb == 0) {  // per-(b, kv-tile) nonzero flags
      if (t < B_) nzbits[t] = 0u;
      __syncthreads();
      if (t < B_*32) {
        int b = t >> 5, kt = t & 31;
        const float* mrow = mask + (size_t)b * S_ + kt*64;
        uint32_t nz = 0;
        for (int c = 0; c < 64; ++c) nz |= (mrow[c] != 1.0f) ? 1u : 0u;
        if (nz) atomicOr(&nzbits[b], 1u << kt);
      }
    }
  } else {
    const int w = bid - 4100;                 // 0..1023
    const int p = w >> 8, ti = w & 255, tr = ti >> 4, tc = ti & 15;
    const float* W = (p == 0) ? Wq : (p == 1) ? Wk : (p == 2) ? Wv : Wo;
#pragma unroll
    for (int it = 0; it < 16; ++it) {
      int idx = it * 256 + t, r = idx >> 6, c = idx & 63;
      tile[r][c] = W[(size_t)(tr*64 + r) * H_ + tc*64 + c];
    }
    __syncthreads();
    u16* outp = wt + (size_t)p * H_ * H_;
#pragma unroll
    for (int it = 0; it < 16; ++it) {
      int idx = it * 256 + t, r = idx >> 6, c = idx & 63;
      outp[(size_t)(tc*64 + r) * H_ + tr*64 + c] = f2bf(tile[c][r]);
    }
  }
}

// ---------------- GEMM (R12 exact): 128x128 block, wave tile 64x64, BK=32, dbuf ------
// Linear [128][32] LDS (64B rows -> 2-way-max conflicts, free). Double-buffered
// global_load_lds with counted vmcnt(4) + raw s_barrier (no vmcnt(0) drain in loop).

__device__ __forceinline__ void gemm_tile(const u16* __restrict__ A, const u16* __restrict__ Bt,
                                          int m0, int n0, u16* As, u16* Bs, f32x4 acc[4][4]) {
  const int tid = threadIdx.x;
  const int lane = tid & 63, wave = tid >> 6;
  const int wr = wave >> 1, wc = wave & 1;
  const int l15 = lane & 15, l4 = lane >> 4;
  const int r0 = tid >> 2, c0 = (tid & 3) * 8;
  const u16* Ap0 = A + (size_t)(m0 + r0) * H_ + c0;
  const u16* Ap1 = A + (size_t)(m0 + 64 + r0) * H_ + c0;
  const u16* Bp0 = Bt + (size_t)(n0 + r0) * H_ + c0;
  const u16* Bp1 = Bt + (size_t)(n0 + 64 + r0) * H_ + c0;
#define GSTAGE(bb, k0) do { \
    gload16(Ap0 + (k0), As + (bb)*4096 + (size_t)tid * 8); \
    gload16(Ap1 + (k0), As + (bb)*4096 + 2048 + (size_t)tid * 8); \
    gload16(Bp0 + (k0), Bs + (bb)*4096 + (size_t)tid * 8); \
    gload16(Bp1 + (k0), Bs + (bb)*4096 + 2048 + (size_t)tid * 8); \
  } while (0)
  GSTAGE(0, 0);
  for (int kt = 0; kt < 32; ++kt) {
    const int cur = kt & 1;
    const int nk = ((kt + 1) & 31) * 32;    // kt=31: dummy restage of k=0 keeps vmcnt uniform
    GSTAGE(cur ^ 1, nk);
    asm volatile("s_waitcnt vmcnt(4)\n\ts_barrier" ::: "memory");  // cur buffer complete
    const u16* Ab = As + cur*4096;
    const u16* Bb = Bs + cur*4096;
    bf16x8 afr[4], bfr[4];
#pragma unroll
    for (int m = 0; m < 4; ++m) afr[m] = *(const bf16x8*)&Ab[(wr*64 + m*16 + l15) * 32 + l4*8];
#pragma unroll
    for (int n = 0; n < 4; ++n) bfr[n] = *(const bf16x8*)&Bb[(wc*64 + n*16 + l15) * 32 + l4*8];
#pragma unroll
    for (int m = 0; m < 4; ++m)
#pragma unroll
      for (int n = 0; n < 4; ++n)
        acc[m][n] = mfma16(afr[m], bfr[n], acc[m][n]);
    asm volatile("s_barrier" ::: "memory");  // all waves done reading buf[cur] before re-stage
  }
  asm volatile("s_waitcnt vmcnt(0)" ::: "memory");   // drain dummy stage
#undef GSTAGE
}

// QKV: C (8192 x 3072). Q (prescaled by 0.125*log2e), K -> [b][h][s][d]; V -> [b][h][d][s]
// with V^T stores packed u16x4 along s (r=0..3 contiguous) to cut write amplification.
__global__ __launch_bounds__(256) void gemm_qkv_kernel(const u16* __restrict__ hs16, const u16* __restrict__ wt,
                                                       const float* __restrict__ bq, const float* __restrict__ bk,
                                                       const float* __restrict__ bv, u16* __restrict__ qkv16) {
  __shared__ __align__(16) u16 As[2*128*32], Bs[2*128*32];
  f32x4 acc[4][4] = {};
  const int lg = xcd_swz(blockIdx.x, 1536);
  const int m0 = (lg / 24) * 128, n0 = (lg % 24) * 128;
  gemm_tile(hs16, wt, m0, n0, As, Bs, acc);
  const int tid = threadIdx.x, lane = tid & 63, wave = tid >> 6;
  const int wr = wave >> 1, wc = wave & 1, l15 = lane & 15, l4 = lane >> 4;
  const int p = n0 >> 10;
  const float* bias = (p == 0) ? bq : (p == 1) ? bk : bv;
  const float qsc = (p == 0) ? 0.18033688f : 1.0f;   // 0.125 * log2(e)
  u16* base = qkv16 + (size_t)p * ((size_t)B_*NH_*S_*HD_);
  if (p == 2) {
    const int b = m0 >> 11;
#pragma unroll
    for (int n = 0; n < 4; ++n) {
      int ncol = (n0 & 1023) + wc*64 + n*16 + l15;
      int h = ncol >> 6, d = ncol & 63;
      float bsv = bias[ncol];
#pragma unroll
      for (int m = 0; m < 4; ++m) {
        int s0 = (m0 & 2047) + wr*64 + m*16 + l4*4;
        u16x4 pk;
#pragma unroll
        for (int r = 0; r < 4; ++r) pk[r] = f2bf(acc[m][n][r] + bsv);
        *(u16x4*)(base + (((size_t)b*NH_ + h)*HD_ + d)*S_ + s0) = pk;
      }
    }
  } else {
#pragma unroll
    for (int n = 0; n < 4; ++n) {
      int ncol = (n0 & 1023) + wc*64 + n*16 + l15;
      int h = ncol >> 6, d = ncol & 63;
      float bsv = bias[ncol];
#pragma unroll
      for (int m = 0; m < 4; ++m) {
#pragma unroll
        for (int r = 0; r < 4; ++r) {
          int row = m0 + wr*64 + m*16 + l4*4 + r;
          int b = row >> 11, s = row & 2047;
          base[(((size_t)b*NH_ + h)*S_ + s)*HD_ + d] = f2bf((acc[m][n][r] + bsv) * qsc);
        }
      }
    }
  }
}

// out-proj: x = ctx16 @ Wo + bo + residual(hs), written BF16 into xb16 (dead hs16
// region) -- LN re-reads it at half the traffic; final fp32 only at the LN write.
__global__ __launch_bounds__(256) void gemm_out_kernel(const u16* __restrict__ ctx16, const u16* __restrict__ wo,
                                                       const float* __restrict__ bo, const float* __restrict__ hs,
                                                       u16* __restrict__ xb16) {
  __shared__ __align__(16) u16 As[2*128*32], Bs[2*128*32];
  f32x4 acc[4][4] = {};
  const int lg = xcd_swz(blockIdx.x, 512);
  const int m0 = (lg / 8) * 128, n0 = (lg % 8) * 128;
  gemm_tile(ctx16, wo, m0, n0, As, Bs, acc);
  const int tid = threadIdx.x, lane = tid & 63, wave = tid >> 6;
  const int wr = wave >> 1, wc = wave & 1, l15 = lane & 15, l4 = lane >> 4;
#pragma unroll
  for (int n = 0; n < 4; ++n) {
    int col = n0 + wc*64 + n*16 + l15;
    float bsv = bo[col];
#pragma unroll
    for (int m = 0; m < 4; ++m) {
#pragma unroll
      for (int r = 0; r < 4; ++r) {
        int row = m0 + wr*64 + m*16 + l4*4 + r;
        size_t off = (size_t)row * H_ + col;
        xb16[off] = f2bf(acc[m][n][r] + bsv + hs[off]);
      }
    }
  }
}

// ---------------- flash attention (R12 exact): 4 waves x 64 q-rows, chainless softmax --
// 2-deep staging (vmcnt(4)), raw exp2, VALU l-sum, epilogue Sc broadcast.

__global__ __launch_bounds__(256, 2) void attn_kernel(const u16* __restrict__ q_, const u16* __restrict__ k_,
                                                      const u16* __restrict__ vt_, const float* __restrict__ madd_g,
                                                      const uint32_t* __restrict__ nzbits,
                                                      u16* __restrict__ ctx16) {
  __shared__ __align__(16) u16 Ks[2][64*64], Vs[2][64*64];
  __shared__ __align__(16) float Sc[4][64];
  const int lgid = xcd_swz(blockIdx.x, 512);
  const int qb = lgid & 7, bh = lgid >> 3, h = bh & 15, b = bh >> 4;
  const int tid = threadIdx.x, lane = tid & 63, wave = tid >> 6;
  const int l31 = lane & 31, hi = lane >> 5;
  const size_t headoff = ((size_t)b * NH_ + h) * ((size_t)S_ * HD_);
  const u16* Q  = q_ + headoff;
  const u16* K  = k_ + headoff;
  const u16* Vt = vt_ + headoff;     // [d][s]
  const uint32_t nzb = nzbits[b];
  const int qbase = qb*256 + wave*64;
  bf16x8 qfA[4], qfB[4];             // strip A rows qbase+l31, strip B rows qbase+32+l31
#pragma unroll
  for (int st = 0; st < 4; ++st) {
    qfA[st] = *(const bf16x8*)(Q + (size_t)(qbase + l31) * HD_ + st*16 + hi*8);
    qfB[st] = *(const bf16x8*)(Q + (size_t)(qbase + 32 + l31) * HD_ + st*16 + hi*8);
  }
  f32x16 O00 = {}, O01 = {}, O10 = {}, O11 = {};
  float lA = 0.f, lB = 0.f;
  const int srow = tid >> 3, sch = tid & 7;
  const int gch = sch ^ (srow & 7);           // inverse-XOR source chunk (involution)
  const int swzA = l31 & 7;                   // read-side row&7

#define STAGE(bb, kt) do { \
    const u16* Kt_ = K + (size_t)(kt) * 64 * HD_; \
    _Pragma("unroll") \
    for (int c = 0; c < 2; ++c) { \
      int row = c*32 + srow; \
      gload16(Kt_ + (size_t)row * HD_ + gch*8, &Ks[bb][c*2048 + (size_t)tid*8]); \
      gload16(Vt + (size_t)row * S_ + (kt)*64 + gch*8, &Vs[bb][c*2048 + (size_t)tid*8]); \
    } \
  } while (0)

  STAGE(0, 0);
  __syncthreads();   // prologue full drain: tile 0 staged

  for (int kt = 0; kt < 32; ++kt) {
    const int cur = kt & 1;
    const int nxt = (kt + 1) & 31;  // kt=31 stages a dummy (tile 0) to keep vmcnt uniform
    STAGE(cur ^ 1, nxt);
    asm volatile("s_waitcnt vmcnt(4)\n\ts_barrier" ::: "memory");
    // ---- QK^T: S^T[kv][q] for both strips; K frags shared ----
    f32x16 sA0 = {}, sA1 = {}, sB0 = {}, sB1 = {};
    __builtin_amdgcn_s_setprio(1);
#pragma unroll
    for (int st = 0; st < 4; ++st) {
      const int kch = ((2*st + hi) ^ swzA) * 8;
      bf16x8 kf0 = *(const bf16x8*)&Ks[cur][l31*64 + kch];
      bf16x8 kf1 = *(const bf16x8*)&Ks[cur][(32 + l31)*64 + kch];
      sA0 = mfma32(kf0, qfA[st], sA0);
      sA1 = mfma32(kf1, qfA[st], sA1);
      sB0 = mfma32(kf0, qfB[st], sB0);
      sB1 = mfma32(kf1, qfB[st], sB1);
    }
    __builtin_amdgcn_s_setprio(0);
    // ---- mask add (rare path), then raw exp2 (no max subtraction) ----
    if ((nzb >> kt) & 1u) {
#pragma unroll
      for (int t = 0; t < 2; ++t) {
        f32x16& sa = t ? sA1 : sA0;
        f32x16& sb2 = t ? sB1 : sB0;
#pragma unroll
        for (int bq = 0; bq < 4; ++bq) {
          f32x4 md = *(const f32x4*)(madd_g + (size_t)b * S_ + kt*64 + t*32 + bq*8 + hi*4);
#pragma unroll
          for (int a = 0; a < 4; ++a) { sa[bq*4 + a] += md[a]; sb2[bq*4 + a] += md[a]; }
        }
      }
    }
#pragma unroll
    for (int r = 0; r < 16; ++r) sA0[r] = EXP2F(sA0[r]);
#pragma unroll
    for (int r = 0; r < 16; ++r) sA1[r] = EXP2F(sA1[r]);
#pragma unroll
    for (int r = 0; r < 16; ++r) sB0[r] = EXP2F(sB0[r]);
#pragma unroll
    for (int r = 0; r < 16; ++r) sB1[r] = EXP2F(sB1[r]);
    // ---- l via in-register add tree (independent of PV; epilogue-only consumer) ----
    {
      float v[16];
#pragma unroll
      for (int r = 0; r < 16; ++r) v[r] = sA0[r] + sA1[r];
#pragma unroll
      for (int r = 0; r < 8; ++r) v[r] += v[r+8];
#pragma unroll
      for (int r = 0; r < 4; ++r) v[r] += v[r+4];
      float rs_ = (v[0] + v[1]) + (v[2] + v[3]);
      int a0 = __float_as_int(rs_), b0 = a0; plswap(a0, b0);
      lA += __int_as_float(a0) + __int_as_float(b0);
#pragma unroll
      for (int r = 0; r < 16; ++r) v[r] = sB0[r] + sB1[r];
#pragma unroll
      for (int r = 0; r < 8; ++r) v[r] += v[r+8];
#pragma unroll
      for (int r = 0; r < 4; ++r) v[r] += v[r+4];
      rs_ = (v[0] + v[1]) + (v[2] + v[3]);
      int a1 = __float_as_int(rs_), b1 = a1; plswap(a1, b1);
      lB += __int_as_float(a1) + __int_as_float(b1);
    }
    // ---- pack P -> bf16 frags (cvt_pk + permlane32_swap); PV; V frags shared ----
    __builtin_amdgcn_s_setprio(1);
#pragma unroll
    for (int ks = 0; ks < 4; ++ks) {
      const f32x16& sa = (ks < 2) ? sA0 : sA1;
      const f32x16& sb2 = (ks < 2) ? sB0 : sB1;
      const int p = ks & 1;
      int pa0 = cvtpk(sa[8*p+0], sa[8*p+1]);
      int pa1 = cvtpk(sa[8*p+2], sa[8*p+3]);
      int pa2 = cvtpk(sa[8*p+4], sa[8*p+5]);
      int pa3 = cvtpk(sa[8*p+6], sa[8*p+7]);
      plswap(pa0, pa2); plswap(pa1, pa3);
      union { i32x4 i; bf16x8 hv; } ua; ua.i = (i32x4){pa0, pa1, pa2, pa3};
      int pb0 = cvtpk(sb2[8*p+0], sb2[8*p+1]);
      int pb1 = cvtpk(sb2[8*p+2], sb2[8*p+3]);
      int pb2 = cvtpk(sb2[8*p+4], sb2[8*p+5]);
      int pb3 = cvtpk(sb2[8*p+6], sb2[8*p+7]);
      plswap(pb0, pb2); plswap(pb1, pb3);
      union { i32x4 i; bf16x8 hv; } ub; ub.i = (i32x4){pb0, pb1, pb2, pb3};
      const int vch = ((2*ks + hi) ^ swzA) * 8;
      bf16x8 vb0 = *(const bf16x8*)&Vs[cur][l31*64 + vch];
      bf16x8 vb1 = *(const bf16x8*)&Vs[cur][(32 + l31)*64 + vch];
      O00 = mfma32(ua.hv, vb0, O00);
      O01 = mfma32(ua.hv, vb1, O01);
      O10 = mfma32(ub.hv, vb0, O10);
      O11 = mfma32(ub.hv, vb1, O11);
    }
    __builtin_amdgcn_s_setprio(0);
    asm volatile("s_barrier" ::: "memory");  // all waves done reading buf[cur]
  }
  asm volatile("s_waitcnt vmcnt(0)" ::: "memory");  // drain dummy stage before LDS dealloc
  // ---- epilogue: broadcast 1/l (q-col layout) to crow layout via wave-private LDS ----
  Sc[wave][l31]      = 1.0f / lA;
  Sc[wave][32 + l31] = 1.0f / lB;
#pragma unroll
  for (int bq = 0; bq < 4; ++bq) {
    f32x4 i0 = *(const f32x4*)&Sc[wave][bq*8 + hi*4];
    f32x4 i1 = *(const f32x4*)&Sc[wave][32 + bq*8 + hi*4];
#pragma unroll
    for (int a = 0; a < 4; ++a) {
      int ql = 8*bq + 4*hi + a, r = bq*4 + a;   // q_local = (r&3) + 8*(r>>2) + 4*hi
      int sA_ = qbase + ql;
      size_t ob0 = ((size_t)(b * S_ + sA_) * NH_ + h) * HD_;
      ctx16[ob0 + l31]      = f2bf(O00[r] * i0[a]);
      ctx16[ob0 + 32 + l31] = f2bf(O01[r] * i0[a]);
      int sB_ = qbase + 32 + ql;
      size_t ob1 = ((size_t)(b * S_ + sB_) * NH_ + h) * HD_;
      ctx16[ob1 + l31]      = f2bf(O10[r] * i1[a]);
      ctx16[ob1 + 32 + l31] = f2bf(O11[r] * i1[a]);
    }
  }
#undef STAGE
}

// ---------------- LayerNorm: read bf16 x (xb16), write fp32 d_out ----------------

__global__ __launch_bounds__(256) void ln_kernel(const u16* __restrict__ xb, float* __restrict__ out,
                                                 const float* __restrict__ g, const float* __restrict__ bb) {
  const int row = blockIdx.x, t = threadIdx.x;
  const u16* xr = xb + (size_t)row * H_;
  u16x4 hv = ((const u16x4*)xr)[t];
  f32x4 v;
  v.x = bf2f(hv[0]); v.y = bf2f(hv[1]); v.z = bf2f(hv[2]); v.w = bf2f(hv[3]);
  float s = v.x + v.y + v.z + v.w;
  float s2 = v.x*v.x + v.y*v.y + v.z*v.z + v.w*v.w;
#pragma unroll
  for (int o = 1; o < 64; o <<= 1) { s += __shfl_xor(s, o, 64); s2 += __shfl_xor(s2, o, 64); }
  __shared__ float red[8];
  const int wave = t >> 6, lane = t & 63;
  if (lane == 0) { red[wave] = s; red[4 + wave] = s2; }
  __syncthreads();
  s = red[0] + red[1] + red[2] + red[3];
  s2 = red[4] + red[5] + red[6] + red[7];
  const float mu = s * (1.0f / H_);
  const float var = s2 * (1.0f / H_) - mu * mu;
  const float rs = rsqrtf(var + 1e-12f);
  f32x4 gg = ((const f32x4*)g)[t], bb4 = ((const f32x4*)bb)[t];
  f32x4 o;
  o.x = (v.x - mu) * rs * gg.x + bb4.x;
  o.y = (v.y - mu) * rs * gg.y + bb4.y;
  o.z = (v.z - mu) * rs * gg.z + bb4.z;
  o.w = (v.w - mu) * rs * gg.w + bb4.w;
  ((f32x4*)(out + (size_t)row * H_))[t] = o;
}

// ---------------- launch ----------------

extern "C" void kernel_launch(void* const* d_in, const int* in_sizes, int n_in,
                              void* d_out, int out_size, void* d_ws, size_t ws_size,
                              hipStream_t stream) {
  (void)in_sizes; (void)n_in; (void)out_size; (void)ws_size;
  const float* hs   = (const float*)d_in[0];
  const float* mask = (const float*)d_in[1];
  const float* Wq = (const float*)d_in[2];
  const float* bq = (const float*)d_in[3];
  const float* Wk = (const float*)d_in[4];
  const float* bk = (const float*)d_in[5];
  const float* Wv = (const float*)d_in[6];
  const float* bv = (const float*)d_in[7];
  const float* Wo = (const float*)d_in[8];
  const float* bo = (const float*)d_in[9];
  const float* lg = (const float*)d_in[10];
  const float* lb = (const float*)d_in[11];
  float* out = (float*)d_out;

  uint8_t* w = (uint8_t*)d_ws;
  u16* hs16  = (u16*)w;                                 // 16 MB: (M,H) bf16; REUSED as xb16 after qkv
  u16* wt16  = (u16*)(w + ((size_t)16 << 20));          //  8 MB: 4x (N,K) bf16 W^T
  u16* qkv16 = (u16*)(w + ((size_t)24 << 20));          // 48 MB: Q,K [b][h][s][d]; V [b][h][d][s]
  u16* ctx16 = (u16*)(w + ((size_t)72 << 20));          // 16 MB: (M,H) bf16
  float* madd_g = (float*)(w + ((size_t)88 << 20));     // 32 KB: (B,S) mask add
  uint32_t* nzbits = (uint32_t*)(w + ((size_t)88 << 20) + 32768);  // 16 B

  const size_t psz = (size_t)B_*NH_*S_*HD_;
  prep_kernel<<<dim3(5124), dim3(256), 0, stream>>>(hs, hs16, mask, madd_g, nzbits,
                                                    Wq, Wk, Wv, Wo, wt16);
  gemm_qkv_kernel<<<dim3(1536), dim3(256), 0, stream>>>(hs16, wt16, bq, bk, bv, qkv16);
  attn_kernel<<<dim3(512), dim3(256), 0, stream>>>(qkv16, qkv16 + psz, qkv16 + 2*psz, madd_g, nzbits, ctx16);
  gemm_out_kernel<<<dim3(512), dim3(256), 0, stream>>>(ctx16, wt16 + (size_t)3*H_*H_, bo, hs, hs16);
  ln_kernel<<<dim3(M_), dim3(256), 0, stream>>>(hs16, out, lg, lb);
}